// Round 7
// baseline (195.384 us; speedup 1.0000x reference)
//
#include <hip/hip_runtime.h>

typedef __attribute__((ext_vector_type(8))) short bf16x8;   // MFMA A/B frag (8 bf16)
typedef __attribute__((ext_vector_type(4))) short bf16x4;   // k16 MFMA A/B frag (4 bf16)
typedef __attribute__((ext_vector_type(4))) float f32x4;    // MFMA C/D frag
typedef __attribute__((ext_vector_type(8))) unsigned short u16x8;
typedef __attribute__((ext_vector_type(4))) unsigned short u16x4;
typedef __attribute__((ext_vector_type(2))) unsigned u32x2;

__device__ __forceinline__ unsigned short f2bf(float f) {
  unsigned u = __builtin_bit_cast(unsigned, f);
  return (unsigned short)((u + 0x7fffu + ((u >> 16) & 1u)) >> 16);
}

__device__ __forceinline__ unsigned cvt_pk_bf16(float lo, float hi) {
  unsigned r;
  asm("v_cvt_pk_bf16_f32 %0, %1, %2" : "=v"(r) : "v"(lo), "v"(hi));
  return r;
}

__device__ __forceinline__ f32x4 mfma16(bf16x4 a, bf16x4 b, f32x4 c) {
#if __has_builtin(__builtin_amdgcn_mfma_f32_16x16x16bf16_1k)
  return __builtin_amdgcn_mfma_f32_16x16x16bf16_1k(a, b, c, 0, 0, 0);
#elif __has_builtin(__builtin_amdgcn_mfma_f32_16x16x16_bf16)
  return __builtin_amdgcn_mfma_f32_16x16x16_bf16(a, b, c, 0, 0, 0);
#else
  f32x4 d;
  asm("v_mfma_f32_16x16x16_bf16 %0, %1, %2, %3" : "=v"(d) : "v"(a), "v"(b), "v"(c));
  return d;
#endif
}

__device__ __forceinline__ void gl_lds16(const void* g, void* l) {
  __builtin_amdgcn_global_load_lds((const __attribute__((address_space(1))) unsigned*)g,
                                   (__attribute__((address_space(3))) unsigned*)l, 16, 0, 0);
}

// ---------------- convert x fp32 -> bf16, 8 elems/thread ----------------
__global__ __launch_bounds__(256) void k_cvt(const float* __restrict__ x,
                                             unsigned short* __restrict__ xb) {
  int i = blockIdx.x * 256 + threadIdx.x;
  const float4* s = (const float4*)x;
  float4 a = s[2 * i], b = s[2 * i + 1];
  u16x8 o;
  o[0] = f2bf(a.x); o[1] = f2bf(a.y); o[2] = f2bf(a.z); o[3] = f2bf(a.w);
  o[4] = f2bf(b.x); o[5] = f2bf(b.y); o[6] = f2bf(b.z); o[7] = f2bf(b.w);
  *(u16x8*)(xb + 8 * (size_t)i) = o;
}

// ------------- transpose+convert weight [K][N] f32 -> [N][K] bf16 -------------
__global__ __launch_bounds__(256) void k_wT(const float* __restrict__ w,
                                            unsigned short* __restrict__ wT,
                                            int Nn, int Kk) {
  __shared__ float tile[32][33];
  const int k0 = blockIdx.x * 32, n0 = blockIdx.y * 32;
  const int t = threadIdx.x;
  const int i = t >> 3, j = (t & 7) * 4;
  float4 v = *(const float4*)(w + (size_t)(k0 + i) * Nn + n0 + j);
  tile[i][j] = v.x; tile[i][j + 1] = v.y; tile[i][j + 2] = v.z; tile[i][j + 3] = v.w;
  __syncthreads();
  const int n = i, k4 = j;
  u16x4 o;
  o[0] = f2bf(tile[k4 + 0][n]); o[1] = f2bf(tile[k4 + 1][n]);
  o[2] = f2bf(tile[k4 + 2][n]); o[3] = f2bf(tile[k4 + 3][n]);
  *(u16x4*)(wT + (size_t)(n0 + n) * Kk + k0 + k4) = o;
}

// ---------------- GEMM: C[M,Nx] = A[M,1024] @ Bt[Nx,1024]^T + bias ----------------
// m97 structure + bijective XCD swizzle (1-D grid, M-major within XCD chunk).
// EPI 0: fp32 row-major out.  EPI 1: scatter to Q/K bf16 (scaled) + V transposed.
template <int EPI>
__global__ __launch_bounds__(256) void k_gemm(const unsigned short* __restrict__ A,
                                              const unsigned short* __restrict__ Bt,
                                              const float* __restrict__ bias, int Nx,
                                              int MT,
                                              float* __restrict__ outF,
                                              unsigned short* __restrict__ Qb,
                                              unsigned short* __restrict__ Kb,
                                              unsigned short* __restrict__ Vb) {
  __shared__ unsigned short As[128 * 32];
  __shared__ unsigned short Bs[128 * 32];
  const int t = threadIdx.x;
  const int nwg = gridDim.x;
  const int wg = (blockIdx.x & 7) * (nwg >> 3) + (blockIdx.x >> 3);  // bijective (nwg%8==0)
  const int brow = (wg % MT) * 128, bcol = (wg / MT) * 128;
  const int lane = t & 63, wid = t >> 6;
  const int wr = (wid >> 1) * 64, wc = (wid & 1) * 64;
  const int g = lane >> 4, qr = lane & 15;
  const f32x4 fzero = {0.f, 0.f, 0.f, 0.f};
  f32x4 acc[4][4];
#pragma unroll
  for (int i = 0; i < 4; ++i)
#pragma unroll
    for (int n = 0; n < 4; ++n) acc[i][n] = fzero;
  const unsigned short* Ag = A + (size_t)(brow + (t >> 2)) * 1024 + (t & 3) * 8;
  const unsigned short* Bg = Bt + (size_t)(bcol + (t >> 2)) * 1024 + (t & 3) * 8;
  unsigned short* Asl = As + t * 8;
  unsigned short* Bsl = Bs + t * 8;
  for (int kt = 0; kt < 32; ++kt) {
    const int k0 = kt * 32;
    gl_lds16(Ag + k0, Asl);
    gl_lds16(Ag + 64 * 1024 + k0, Asl + 2048);
    gl_lds16(Bg + k0, Bsl);
    gl_lds16(Bg + 64 * 1024 + k0, Bsl + 2048);
    __syncthreads();
    bf16x8 a[4], b[4];
#pragma unroll
    for (int i = 0; i < 4; ++i) a[i] = *(const bf16x8*)&As[(wr + i * 16 + qr) * 32 + g * 8];
#pragma unroll
    for (int n = 0; n < 4; ++n) b[n] = *(const bf16x8*)&Bs[(wc + n * 16 + qr) * 32 + g * 8];
#pragma unroll
    for (int i = 0; i < 4; ++i)
#pragma unroll
      for (int n = 0; n < 4; ++n)
        acc[i][n] = __builtin_amdgcn_mfma_f32_16x16x32_bf16(a[i], b[n], acc[i][n], 0, 0, 0);
    __syncthreads();
  }
#pragma unroll
  for (int i = 0; i < 4; ++i) {
#pragma unroll
    for (int n = 0; n < 4; ++n) {
      const int col = bcol + wc + n * 16 + qr;
      const float bv = bias[col];
      float v4[4];
#pragma unroll
      for (int r = 0; r < 4; ++r) v4[r] = acc[i][n][r] + bv;
      const int row0 = brow + wr + i * 16 + g * 4;
      if constexpr (EPI == 0) {
#pragma unroll
        for (int r = 0; r < 4; ++r) outF[(size_t)(row0 + r) * Nx + col] = v4[r];
      } else {
        const int bb = row0 >> 11, tkn0 = row0 & 2047;
        const unsigned c = (unsigned)col;
        const unsigned h = c / 192u;
        const unsigned rem = c - h * 192u;
        const unsigned which = rem >> 6, d = rem & 63u;
        if (which == 2u) {  // V transposed [bh][d][tkn]: 4 consecutive tokens -> 8B store
          u16x4 pk;
#pragma unroll
          for (int r = 0; r < 4; ++r) pk[r] = f2bf(v4[r]);
          *(u16x4*)&Vb[(size_t)(((unsigned)bb * 16u + h) * 64u + d) * 2048u + (unsigned)tkn0] = pk;
        } else {
          // Q gets extra log2e fold (softmax computed in exp2 domain)
          const float sc = (which == 0u) ? (0.35355339059327373f * 1.4426950408889634f)
                                         : 0.35355339059327373f;
          unsigned short* dst = (which == 0u) ? Qb : Kb;
#pragma unroll
          for (int r = 0; r < 4; ++r)
            dst[(size_t)(((unsigned)bb * 16u + h) * 2048u + (unsigned)(tkn0 + r)) * 64u + d] =
                f2bf(v4[r] * sc);
        }
      }
    }
  }
}

// -------- flash attention: 8 waves x 32 q-rows (2 groups), KVBLK=64, LDS dbuf --------
// No-max exp2 softmax; P stays in registers (k16 MFMA B-frag matches QK^T C layout).
__global__ __launch_bounds__(512, 4) void k_attn(const unsigned short* __restrict__ Qb,
                                                 const unsigned short* __restrict__ Kb,
                                                 const unsigned short* __restrict__ Vt,
                                                 unsigned short* __restrict__ Ao) {
  __shared__ unsigned short Kl[2][64][64];     // [buf][key][d], rows XOR-swizzled
  __shared__ unsigned short Vl[2][64][64];     // [buf][d][key], rows XOR-swizzled
  const int bid = blockIdx.x;
  const int bh = (bid & 7) * 8 + ((bid >> 3) & 7);  // XCD x owns bh 8x..8x+7 (K/V fits its L2)
  const int qt = bid >> 6;                          // 8 q-tiles of 256 rows
  const int t = threadIdx.x, lane = t & 63, w = t >> 6;  // 8 waves
  const int g = lane >> 4, q = lane & 15;
  const int q0 = qt * 256 + w * 32;
  const unsigned short* Qbase = Qb + ((size_t)bh * 2048 + q0) * 64;
  const char* Kg = (const char*)(Kb + (size_t)bh * 2048 * 64);
  const char* Vg = (const char*)(Vt + (size_t)bh * 64 * 2048);
  // staging: wave w stages rows 8w..8w+7 of K and of V(d); pre-swizzled global src
  const int lr = lane >> 3, lc = lane & 7;
  const int swz = (lc ^ lr) << 4;
  const char* Ksrc = Kg + (size_t)(8 * w + lr) * 128 + swz;
  const char* Vsrc = Vg + (size_t)(8 * w + lr) * 4096 + swz;
  unsigned short* Kd[2], *Vd[2];
  Kd[0] = &Kl[0][8 * w][0] + lane * 8;
  Kd[1] = &Kl[1][8 * w][0] + lane * 8;
  Vd[0] = &Vl[0][8 * w][0] + lane * 8;
  Vd[1] = &Vl[1][8 * w][0] + lane * 8;

#define STAGE(buf, it_)                              \
  do {                                               \
    gl_lds16(Ksrc + (size_t)(it_) * 8192, Kd[buf]);  \
    gl_lds16(Vsrc + (size_t)(it_) * 128, Vd[buf]);   \
  } while (0)

  bf16x8 qf[2][2];
#pragma unroll
  for (int G = 0; G < 2; ++G)
#pragma unroll
    for (int h = 0; h < 2; ++h)
      qf[G][h] = *(const bf16x8*)(Qbase + (size_t)(G * 16 + q) * 64 + h * 32 + g * 8);
  const f32x4 fzero = {0.f, 0.f, 0.f, 0.f};
  f32x4 o0[4], o1[4];
#pragma unroll
  for (int i = 0; i < 4; ++i) { o0[i] = fzero; o1[i] = fzero; }
  float l0 = 0.f, l1 = 0.f;  // lane-partial softmax denominators

  STAGE(0, 0);
  __syncthreads();

  for (int it = 0; it < 32; ++it) {
    const int cur = it & 1;
    if (it < 31) STAGE(cur ^ 1, it + 1);
    // ---- QK^T (swapped: A=K rows=keys, B=Q cols=queries), both groups ----
    f32x4 s0[4], s1[4];
    __builtin_amdgcn_s_setprio(1);
#pragma unroll
    for (int kf = 0; kf < 4; ++kf) {
      const int row = kf * 16 + q;
      const char* kp = (const char*)&Kl[cur][row][0];
      const int sw = (row & 7) << 4;
      bf16x8 kaL = *(const bf16x8*)(kp + ((g * 16) ^ sw));
      bf16x8 kaH = *(const bf16x8*)(kp + ((64 + g * 16) ^ sw));
      s0[kf] = __builtin_amdgcn_mfma_f32_16x16x32_bf16(kaL, qf[0][0], fzero, 0, 0, 0);
      s0[kf] = __builtin_amdgcn_mfma_f32_16x16x32_bf16(kaH, qf[0][1], s0[kf], 0, 0, 0);
      s1[kf] = __builtin_amdgcn_mfma_f32_16x16x32_bf16(kaL, qf[1][0], fzero, 0, 0, 0);
      s1[kf] = __builtin_amdgcn_mfma_f32_16x16x32_bf16(kaH, qf[1][1], s1[kf], 0, 0, 0);
    }
    __builtin_amdgcn_s_setprio(0);
    // ---- per-kf: exp2 -> in-register P frags -> k16 PV MFMAs (no P LDS bounce) ----
#pragma unroll
    for (int kf = 0; kf < 4; ++kf) {
      const float e00 = __builtin_amdgcn_exp2f(s0[kf][0]);
      const float e01 = __builtin_amdgcn_exp2f(s0[kf][1]);
      const float e02 = __builtin_amdgcn_exp2f(s0[kf][2]);
      const float e03 = __builtin_amdgcn_exp2f(s0[kf][3]);
      l0 += (e00 + e01) + (e02 + e03);
      u32x2 pk0;
      pk0[0] = cvt_pk_bf16(e00, e01);
      pk0[1] = cvt_pk_bf16(e02, e03);
      const bf16x4 pf0 = __builtin_bit_cast(bf16x4, pk0);
      const float e10 = __builtin_amdgcn_exp2f(s1[kf][0]);
      const float e11 = __builtin_amdgcn_exp2f(s1[kf][1]);
      const float e12 = __builtin_amdgcn_exp2f(s1[kf][2]);
      const float e13 = __builtin_amdgcn_exp2f(s1[kf][3]);
      l1 += (e10 + e11) + (e12 + e13);
      u32x2 pk1;
      pk1[0] = cvt_pk_bf16(e10, e11);
      pk1[1] = cvt_pk_bf16(e12, e13);
      const bf16x4 pf1 = __builtin_bit_cast(bf16x4, pk1);
      const int off = 32 * kf + 8 * g;  // byte offset of keys 16kf+4g..+3 in V row
#pragma unroll
      for (int dblk = 0; dblk < 4; ++dblk) {
        const int row = dblk * 16 + q;
        const char* vp = (const char*)&Vl[cur][row][0];
        const int sw = (row & 7) << 4;
        const bf16x4 vf = *(const bf16x4*)(vp + (off ^ sw));
        o0[dblk] = mfma16(vf, pf0, o0[dblk]);
        o1[dblk] = mfma16(vf, pf1, o1[dblk]);
      }
    }
    __syncthreads();
  }
#undef STAGE
  // finalize l (one cross-lane reduce over g), normalize, write O^T
  l0 += __shfl_xor(l0, 16); l0 += __shfl_xor(l0, 32);
  l1 += __shfl_xor(l1, 16); l1 += __shfl_xor(l1, 32);
  const float li0 = 1.0f / l0, li1 = 1.0f / l1;
  const int bb = bh >> 4, hh = bh & 15;
  {
    unsigned short* ob = Ao + ((size_t)bb * 2048 + q0 + q) * 1024 + hh * 64 + 4 * g;
#pragma unroll
    for (int dblk = 0; dblk < 4; ++dblk) {
      u16x4 pk;
#pragma unroll
      for (int r = 0; r < 4; ++r) pk[r] = f2bf(o0[dblk][r] * li0);
      *(u16x4*)(ob + dblk * 16) = pk;
    }
  }
  {
    unsigned short* ob = Ao + ((size_t)bb * 2048 + q0 + 16 + q) * 1024 + hh * 64 + 4 * g;
#pragma unroll
    for (int dblk = 0; dblk < 4; ++dblk) {
      u16x4 pk;
#pragma unroll
      for (int r = 0; r < 4; ++r) pk[r] = f2bf(o1[dblk][r] * li1);
      *(u16x4*)(ob + dblk * 16) = pk;
    }
  }
}

extern "C" void kernel_launch(void* const* d_in, const int* in_sizes, int n_in,
                              void* d_out, int out_size, void* d_ws, size_t ws_size,
                              hipStream_t stream) {
  const float* x = (const float*)d_in[0];
  const float* w_qkv = (const float*)d_in[1];
  const float* b_qkv = (const float*)d_in[2];
  const float* w_proj = (const float*)d_in[3];
  const float* b_proj = (const float*)d_in[4];
  float* out = (float*)d_out;
  char* ws = (char*)d_ws;
  unsigned short* xb = (unsigned short*)(ws);                  // 16 MB  [8192,1024] bf16
  unsigned short* wqkvT = (unsigned short*)(ws + 16777216);    // 6 MB   [3072,1024]
  unsigned short* wprojT = (unsigned short*)(ws + 23068672);   // 2 MB   [1024,1024]
  unsigned short* Qb = (unsigned short*)(ws + 25165824);       // 16 MB  [bh][2048][64] (log2e folded)
  unsigned short* Kb = (unsigned short*)(ws + 41943040);       // 16 MB  [bh][2048][64]
  unsigned short* Vt = (unsigned short*)(ws + 58720256);       // 16 MB  [bh][64][2048]
  unsigned short* Ao = xb;  // reuse (xb dead after GEMM1)

  hipLaunchKernelGGL(k_cvt, dim3(4096), dim3(256), 0, stream, x, xb);
  hipLaunchKernelGGL(k_wT, dim3(32, 96), dim3(256), 0, stream, w_qkv, wqkvT, 3072, 1024);
  hipLaunchKernelGGL(k_wT, dim3(32, 32), dim3(256), 0, stream, w_proj, wprojT, 1024, 1024);
  hipLaunchKernelGGL((k_gemm<1>), dim3(1536), dim3(256), 0, stream,
                     xb, wqkvT, b_qkv, 3072, 64, (float*)nullptr, Qb, Kb, Vt);
  hipLaunchKernelGGL(k_attn, dim3(512), dim3(512), 0, stream, Qb, Kb, Vt, Ao);
  hipLaunchKernelGGL((k_gemm<0>), dim3(512), dim3(256), 0, stream,
                     Ao, wprojT, b_proj, 1024, 64, out,
                     (unsigned short*)nullptr, (unsigned short*)nullptr, (unsigned short*)nullptr);
}

// Round 9
// 189.833 us; speedup vs baseline: 1.0292x; 1.0292x over previous
//
#include <hip/hip_runtime.h>

typedef __attribute__((ext_vector_type(8))) short bf16x8;   // MFMA A/B frag (8 bf16)
typedef __attribute__((ext_vector_type(4))) float f32x4;    // MFMA C/D frag
typedef __attribute__((ext_vector_type(8))) unsigned short u16x8;
typedef __attribute__((ext_vector_type(4))) unsigned short u16x4;
typedef __attribute__((ext_vector_type(2))) unsigned u32x2;

__device__ __forceinline__ unsigned short f2bf(float f) {
  unsigned u = __builtin_bit_cast(unsigned, f);
  return (unsigned short)((u + 0x7fffu + ((u >> 16) & 1u)) >> 16);
}

__device__ __forceinline__ unsigned cvt_pk_bf16(float lo, float hi) {
  unsigned r;
  asm("v_cvt_pk_bf16_f32 %0, %1, %2" : "=v"(r) : "v"(lo), "v"(hi));
  return r;
}

__device__ __forceinline__ void gl_lds16(const void* g, void* l) {
  __builtin_amdgcn_global_load_lds((const __attribute__((address_space(1))) unsigned*)g,
                                   (__attribute__((address_space(3))) unsigned*)l, 16, 0, 0);
}

// ---------------- convert x fp32 -> bf16, 8 elems/thread ----------------
__global__ __launch_bounds__(256) void k_cvt(const float* __restrict__ x,
                                             unsigned short* __restrict__ xb) {
  int i = blockIdx.x * 256 + threadIdx.x;
  const float4* s = (const float4*)x;
  float4 a = s[2 * i], b = s[2 * i + 1];
  u16x8 o;
  o[0] = f2bf(a.x); o[1] = f2bf(a.y); o[2] = f2bf(a.z); o[3] = f2bf(a.w);
  o[4] = f2bf(b.x); o[5] = f2bf(b.y); o[6] = f2bf(b.z); o[7] = f2bf(b.w);
  *(u16x8*)(xb + 8 * (size_t)i) = o;
}

// ------------- transpose+convert weight [K][N] f32 -> [N][K] bf16 -------------
__global__ __launch_bounds__(256) void k_wT(const float* __restrict__ w,
                                            unsigned short* __restrict__ wT,
                                            int Nn, int Kk) {
  __shared__ float tile[32][33];
  const int k0 = blockIdx.x * 32, n0 = blockIdx.y * 32;
  const int t = threadIdx.x;
  const int i = t >> 3, j = (t & 7) * 4;
  float4 v = *(const float4*)(w + (size_t)(k0 + i) * Nn + n0 + j);
  tile[i][j] = v.x; tile[i][j + 1] = v.y; tile[i][j + 2] = v.z; tile[i][j + 3] = v.w;
  __syncthreads();
  const int n = i, k4 = j;
  u16x4 o;
  o[0] = f2bf(tile[k4 + 0][n]); o[1] = f2bf(tile[k4 + 1][n]);
  o[2] = f2bf(tile[k4 + 2][n]); o[3] = f2bf(tile[k4 + 3][n]);
  *(u16x4*)(wT + (size_t)(n0 + n) * Kk + k0 + k4) = o;
}

// ---------------- GEMM: C[M,Nx] = A[M,1024] @ Bt[Nx,1024]^T + bias ----------------
// 128x128 tile, BK=64 (16 barrier-pairs instead of 32), row-XOR-swizzled LDS
// (pre-swizzled global source for global_load_lds, XOR on frag reads -> ~2-way banks).
// EPI 0: fp32 row-major out.  EPI 1: scatter to Q/K bf16 (scaled) + V transposed.
template <int EPI>
__global__ __launch_bounds__(256) void k_gemm(const unsigned short* __restrict__ A,
                                              const unsigned short* __restrict__ Bt,
                                              const float* __restrict__ bias, int Nx,
                                              int MT,
                                              float* __restrict__ outF,
                                              unsigned short* __restrict__ Qb,
                                              unsigned short* __restrict__ Kb,
                                              unsigned short* __restrict__ Vb) {
  __shared__ __attribute__((aligned(16))) unsigned short As[128 * 64];
  __shared__ __attribute__((aligned(16))) unsigned short Bs[128 * 64];
  const int t = threadIdx.x;
  const int nwg = gridDim.x;
  const int wg = (blockIdx.x & 7) * (nwg >> 3) + (blockIdx.x >> 3);  // bijective (nwg%8==0)
  const int brow = (wg % MT) * 128, bcol = (wg / MT) * 128;
  const int lane = t & 63, wid = t >> 6;
  const int wr = (wid >> 1) * 64, wc = (wid & 1) * 64;
  const int g = lane >> 4, qr = lane & 15;
  const f32x4 fzero = {0.f, 0.f, 0.f, 0.f};
  f32x4 acc[4][4];
#pragma unroll
  for (int i = 0; i < 4; ++i)
#pragma unroll
    for (int n = 0; n < 4; ++n) acc[i][n] = fzero;
  // staging: thread t -> tile row (32c + t/8), swizzled k-chunk ((t&7)^(t>>3 &7))*8 elems
  const int strow = t >> 3;                       // 0..31
  const int swz8 = ((t & 7) ^ (strow & 7)) << 3;  // shorts
  const unsigned short* Ag = A + (size_t)(brow + strow) * 1024 + swz8;
  const unsigned short* Bg = Bt + (size_t)(bcol + strow) * 1024 + swz8;
  unsigned short* Asl = As + t * 8;
  unsigned short* Bsl = Bs + t * 8;
  for (int kt = 0; kt < 16; ++kt) {
    const int k0 = kt * 64;
    gl_lds16(Ag + k0, Asl);
    gl_lds16(Ag + 32 * 1024 + k0, Asl + 2048);
    gl_lds16(Ag + 64 * 1024 + k0, Asl + 4096);
    gl_lds16(Ag + 96 * 1024 + k0, Asl + 6144);
    gl_lds16(Bg + k0, Bsl);
    gl_lds16(Bg + 32 * 1024 + k0, Bsl + 2048);
    gl_lds16(Bg + 64 * 1024 + k0, Bsl + 4096);
    gl_lds16(Bg + 96 * 1024 + k0, Bsl + 6144);
    __syncthreads();
    // khalf = 0
    {
      bf16x8 a[4], b[4];
#pragma unroll
      for (int i = 0; i < 4; ++i) {
        const int r = wr + i * 16 + qr;
        a[i] = *(const bf16x8*)&As[r * 64 + ((g ^ (r & 7)) << 3)];
      }
#pragma unroll
      for (int n = 0; n < 4; ++n) {
        const int r = wc + n * 16 + qr;
        b[n] = *(const bf16x8*)&Bs[r * 64 + ((g ^ (r & 7)) << 3)];
      }
#pragma unroll
      for (int i = 0; i < 4; ++i)
#pragma unroll
        for (int n = 0; n < 4; ++n)
          acc[i][n] = __builtin_amdgcn_mfma_f32_16x16x32_bf16(a[i], b[n], acc[i][n], 0, 0, 0);
    }
    // khalf = 1 (k elems +32 -> chunk index +4)
    {
      bf16x8 a[4], b[4];
#pragma unroll
      for (int i = 0; i < 4; ++i) {
        const int r = wr + i * 16 + qr;
        a[i] = *(const bf16x8*)&As[r * 64 + (((4 + g) ^ (r & 7)) << 3)];
      }
#pragma unroll
      for (int n = 0; n < 4; ++n) {
        const int r = wc + n * 16 + qr;
        b[n] = *(const bf16x8*)&Bs[r * 64 + (((4 + g) ^ (r & 7)) << 3)];
      }
#pragma unroll
      for (int i = 0; i < 4; ++i)
#pragma unroll
        for (int n = 0; n < 4; ++n)
          acc[i][n] = __builtin_amdgcn_mfma_f32_16x16x32_bf16(a[i], b[n], acc[i][n], 0, 0, 0);
    }
    __syncthreads();
  }
#pragma unroll
  for (int i = 0; i < 4; ++i) {
#pragma unroll
    for (int n = 0; n < 4; ++n) {
      const int col = bcol + wc + n * 16 + qr;
      const float bv = bias[col];
      float v4[4];
#pragma unroll
      for (int r = 0; r < 4; ++r) v4[r] = acc[i][n][r] + bv;
      const int row0 = brow + wr + i * 16 + g * 4;
      if constexpr (EPI == 0) {
#pragma unroll
        for (int r = 0; r < 4; ++r) outF[(size_t)(row0 + r) * Nx + col] = v4[r];
      } else {
        const int bb = row0 >> 11, tkn0 = row0 & 2047;
        const unsigned c = (unsigned)col;
        const unsigned h = c / 192u;
        const unsigned rem = c - h * 192u;
        const unsigned which = rem >> 6, d = rem & 63u;
        if (which == 2u) {  // V transposed [bh][d][tkn]: 4 consecutive tokens -> 8B store
          u16x4 pk;
#pragma unroll
          for (int r = 0; r < 4; ++r) pk[r] = f2bf(v4[r]);
          *(u16x4*)&Vb[(size_t)(((unsigned)bb * 16u + h) * 64u + d) * 2048u + (unsigned)tkn0] = pk;
        } else {
          // Q gets extra log2e fold (softmax computed in exp2 domain)
          const float sc = (which == 0u) ? (0.35355339059327373f * 1.4426950408889634f)
                                         : 0.35355339059327373f;
          unsigned short* dst = (which == 0u) ? Qb : Kb;
#pragma unroll
          for (int r = 0; r < 4; ++r)
            dst[(size_t)(((unsigned)bb * 16u + h) * 2048u + (unsigned)(tkn0 + r)) * 64u + d] =
                f2bf(v4[r] * sc);
        }
      }
    }
  }
}

// -------- flash attention: 8 waves x 32 q-rows (2 groups), KVBLK=64, LDS dbuf --------
// No-max softmax (exp2 domain; |S_log2| << 126 always for sane inputs), O^T accum.
// (Verified round-6 kernel, restored unchanged.)
__global__ __launch_bounds__(512, 4) void k_attn(const unsigned short* __restrict__ Qb,
                                                 const unsigned short* __restrict__ Kb,
                                                 const unsigned short* __restrict__ Vt,
                                                 unsigned short* __restrict__ Ao) {
  __shared__ __attribute__((aligned(16))) unsigned short Kl[2][64][64];
  __shared__ __attribute__((aligned(16))) unsigned short Vl[2][64][64];
  __shared__ __attribute__((aligned(16))) unsigned short Pl[8][2][16][72];
  const int bid = blockIdx.x;
  const int bh = (bid & 7) * 8 + ((bid >> 3) & 7);  // XCD x owns bh 8x..8x+7 (K/V fits its L2)
  const int qt = bid >> 6;                          // 8 q-tiles of 256 rows
  const int t = threadIdx.x, lane = t & 63, w = t >> 6;  // 8 waves
  const int g = lane >> 4, q = lane & 15;
  const int q0 = qt * 256 + w * 32;
  const unsigned short* Qbase = Qb + ((size_t)bh * 2048 + q0) * 64;
  const char* Kg = (const char*)(Kb + (size_t)bh * 2048 * 64);
  const char* Vg = (const char*)(Vt + (size_t)bh * 64 * 2048);
  const int lr = lane >> 3, lc = lane & 7;
  const int swz = (lc ^ lr) << 4;
  const char* Ksrc = Kg + (size_t)(8 * w + lr) * 128 + swz;
  const char* Vsrc = Vg + (size_t)(8 * w + lr) * 4096 + swz;
  unsigned short* Kd[2], *Vd[2];
  Kd[0] = &Kl[0][8 * w][0] + lane * 8;
  Kd[1] = &Kl[1][8 * w][0] + lane * 8;
  Vd[0] = &Vl[0][8 * w][0] + lane * 8;
  Vd[1] = &Vl[1][8 * w][0] + lane * 8;

#define STAGE(buf, it_)                              \
  do {                                               \
    gl_lds16(Ksrc + (size_t)(it_) * 8192, Kd[buf]);  \
    gl_lds16(Vsrc + (size_t)(it_) * 128, Vd[buf]);   \
  } while (0)

  bf16x8 qf[2][2];
#pragma unroll
  for (int G = 0; G < 2; ++G)
#pragma unroll
    for (int h = 0; h < 2; ++h)
      qf[G][h] = *(const bf16x8*)(Qbase + (size_t)(G * 16 + q) * 64 + h * 32 + g * 8);
  const f32x4 fzero = {0.f, 0.f, 0.f, 0.f};
  f32x4 o0[4], o1[4];
#pragma unroll
  for (int i = 0; i < 4; ++i) { o0[i] = fzero; o1[i] = fzero; }
  float l0 = 0.f, l1 = 0.f;  // lane-partial softmax denominators

  STAGE(0, 0);
  __syncthreads();

  for (int it = 0; it < 32; ++it) {
    const int cur = it & 1;
    if (it < 31) STAGE(cur ^ 1, it + 1);
    // ---- QK^T (swapped: A=K rows=keys, B=Q cols=queries), both groups ----
    f32x4 s0[4], s1[4];
    __builtin_amdgcn_s_setprio(1);
#pragma unroll
    for (int kf = 0; kf < 4; ++kf) {
      const int row = kf * 16 + q;
      const char* kp = (const char*)&Kl[cur][row][0];
      const int sw = (row & 7) << 4;
      bf16x8 kaL = *(const bf16x8*)(kp + ((g * 16) ^ sw));
      bf16x8 kaH = *(const bf16x8*)(kp + ((64 + g * 16) ^ sw));
      s0[kf] = __builtin_amdgcn_mfma_f32_16x16x32_bf16(kaL, qf[0][0], fzero, 0, 0, 0);
      s0[kf] = __builtin_amdgcn_mfma_f32_16x16x32_bf16(kaH, qf[0][1], s0[kf], 0, 0, 0);
      s1[kf] = __builtin_amdgcn_mfma_f32_16x16x32_bf16(kaL, qf[1][0], fzero, 0, 0, 0);
      s1[kf] = __builtin_amdgcn_mfma_f32_16x16x32_bf16(kaH, qf[1][1], s1[kf], 0, 0, 0);
    }
    __builtin_amdgcn_s_setprio(0);
    // ---- softmax numerators: P = exp2(S), lane-partial l accumulation ----
    {
      unsigned short* Pw = &Pl[w][0][q][0];
#pragma unroll
      for (int kf = 0; kf < 4; ++kf) {
        const float e0 = __builtin_amdgcn_exp2f(s0[kf][0]);
        const float e1 = __builtin_amdgcn_exp2f(s0[kf][1]);
        const float e2 = __builtin_amdgcn_exp2f(s0[kf][2]);
        const float e3 = __builtin_amdgcn_exp2f(s0[kf][3]);
        l0 += (e0 + e1) + (e2 + e3);
        u32x2 pk;
        pk[0] = cvt_pk_bf16(e0, e1);
        pk[1] = cvt_pk_bf16(e2, e3);
        *(u32x2*)(Pw + (8 * kf + 2 * g) * 2) = pk;
      }
    }
    {
      unsigned short* Pw = &Pl[w][1][q][0];
#pragma unroll
      for (int kf = 0; kf < 4; ++kf) {
        const float e0 = __builtin_amdgcn_exp2f(s1[kf][0]);
        const float e1 = __builtin_amdgcn_exp2f(s1[kf][1]);
        const float e2 = __builtin_amdgcn_exp2f(s1[kf][2]);
        const float e3 = __builtin_amdgcn_exp2f(s1[kf][3]);
        l1 += (e0 + e1) + (e2 + e3);
        u32x2 pk;
        pk[0] = cvt_pk_bf16(e0, e1);
        pk[1] = cvt_pk_bf16(e2, e3);
        *(u32x2*)(Pw + (8 * kf + 2 * g) * 2) = pk;
      }
    }
    asm volatile("" ::: "memory");
    // ---- PV, O^T accumulation: D[row=d][col=query] (query lane-local) ----
    const bf16x8 pa00 = *(const bf16x8*)&Pl[w][0][q][g * 8];
    const bf16x8 pa01 = *(const bf16x8*)&Pl[w][0][q][32 + g * 8];
    const bf16x8 pa10 = *(const bf16x8*)&Pl[w][1][q][g * 8];
    const bf16x8 pa11 = *(const bf16x8*)&Pl[w][1][q][32 + g * 8];
    __builtin_amdgcn_s_setprio(1);
#pragma unroll
    for (int dblk = 0; dblk < 4; ++dblk) {
      const int row = dblk * 16 + q;
      const char* vp = (const char*)&Vl[cur][row][0];
      const int sw = (row & 7) << 4;
      bf16x8 vL = *(const bf16x8*)(vp + ((g * 16) ^ sw));
      bf16x8 vH = *(const bf16x8*)(vp + ((64 + g * 16) ^ sw));
      o0[dblk] = __builtin_amdgcn_mfma_f32_16x16x32_bf16(vL, pa00, o0[dblk], 0, 0, 0);
      o0[dblk] = __builtin_amdgcn_mfma_f32_16x16x32_bf16(vH, pa01, o0[dblk], 0, 0, 0);
      o1[dblk] = __builtin_amdgcn_mfma_f32_16x16x32_bf16(vL, pa10, o1[dblk], 0, 0, 0);
      o1[dblk] = __builtin_amdgcn_mfma_f32_16x16x32_bf16(vH, pa11, o1[dblk], 0, 0, 0);
    }
    __builtin_amdgcn_s_setprio(0);
    __syncthreads();
  }
#undef STAGE
  // finalize l (one cross-lane reduce over g), normalize, write O^T
  l0 += __shfl_xor(l0, 16); l0 += __shfl_xor(l0, 32);
  l1 += __shfl_xor(l1, 16); l1 += __shfl_xor(l1, 32);
  const float li0 = 1.0f / l0, li1 = 1.0f / l1;
  const int bb = bh >> 4, hh = bh & 15;
  {
    unsigned short* ob = Ao + ((size_t)bb * 2048 + q0 + q) * 1024 + hh * 64 + 4 * g;
#pragma unroll
    for (int dblk = 0; dblk < 4; ++dblk) {
      u16x4 pk;
#pragma unroll
      for (int r = 0; r < 4; ++r) pk[r] = f2bf(o0[dblk][r] * li0);
      *(u16x4*)(ob + dblk * 16) = pk;
    }
  }
  {
    unsigned short* ob = Ao + ((size_t)bb * 2048 + q0 + 16 + q) * 1024 + hh * 64 + 4 * g;
#pragma unroll
    for (int dblk = 0; dblk < 4; ++dblk) {
      u16x4 pk;
#pragma unroll
      for (int r = 0; r < 4; ++r) pk[r] = f2bf(o1[dblk][r] * li1);
      *(u16x4*)(ob + dblk * 16) = pk;
    }
  }
}

extern "C" void kernel_launch(void* const* d_in, const int* in_sizes, int n_in,
                              void* d_out, int out_size, void* d_ws, size_t ws_size,
                              hipStream_t stream) {
  const float* x = (const float*)d_in[0];
  const float* w_qkv = (const float*)d_in[1];
  const float* b_qkv = (const float*)d_in[2];
  const float* w_proj = (const float*)d_in[3];
  const float* b_proj = (const float*)d_in[4];
  float* out = (float*)d_out;
  char* ws = (char*)d_ws;
  unsigned short* xb = (unsigned short*)(ws);                  // 16 MB  [8192,1024] bf16
  unsigned short* wqkvT = (unsigned short*)(ws + 16777216);    // 6 MB   [3072,1024]
  unsigned short* wprojT = (unsigned short*)(ws + 23068672);   // 2 MB   [1024,1024]
  unsigned short* Qb = (unsigned short*)(ws + 25165824);       // 16 MB  [bh][2048][64] (log2e folded)
  unsigned short* Kb = (unsigned short*)(ws + 41943040);       // 16 MB  [bh][2048][64]
  unsigned short* Vt = (unsigned short*)(ws + 58720256);       // 16 MB  [bh][64][2048]
  unsigned short* Ao = xb;  // reuse (xb dead after GEMM1)

  hipLaunchKernelGGL(k_cvt, dim3(4096), dim3(256), 0, stream, x, xb);
  hipLaunchKernelGGL(k_wT, dim3(32, 96), dim3(256), 0, stream, w_qkv, wqkvT, 3072, 1024);
  hipLaunchKernelGGL(k_wT, dim3(32, 32), dim3(256), 0, stream, w_proj, wprojT, 1024, 1024);
  hipLaunchKernelGGL((k_gemm<1>), dim3(1536), dim3(256), 0, stream,
                     xb, wqkvT, b_qkv, 3072, 64, (float*)nullptr, Qb, Kb, Vt);
  hipLaunchKernelGGL(k_attn, dim3(512), dim3(512), 0, stream, Qb, Kb, Vt, Ao);
  hipLaunchKernelGGL((k_gemm<0>), dim3(512), dim3(256), 0, stream,
                     Ao, wprojT, b_proj, 1024, 64, out,
                     (unsigned short*)nullptr, (unsigned short*)nullptr, (unsigned short*)nullptr);
}

// Round 11
// 179.022 us; speedup vs baseline: 1.0914x; 1.0604x over previous
//
#include <hip/hip_runtime.h>

typedef __attribute__((ext_vector_type(8))) short bf16x8;   // MFMA A/B frag (8 bf16)
typedef __attribute__((ext_vector_type(4))) float f32x4;    // MFMA C/D frag
typedef __attribute__((ext_vector_type(8))) unsigned short u16x8;
typedef __attribute__((ext_vector_type(4))) unsigned short u16x4;
typedef __attribute__((ext_vector_type(2))) unsigned u32x2;

__device__ __forceinline__ unsigned short f2bf(float f) {
  unsigned u = __builtin_bit_cast(unsigned, f);
  return (unsigned short)((u + 0x7fffu + ((u >> 16) & 1u)) >> 16);
}

__device__ __forceinline__ unsigned cvt_pk_bf16(float lo, float hi) {
  unsigned r;
  asm("v_cvt_pk_bf16_f32 %0, %1, %2" : "=v"(r) : "v"(lo), "v"(hi));
  return r;
}

__device__ __forceinline__ void gl_lds16(const void* g, void* l) {
  __builtin_amdgcn_global_load_lds((const __attribute__((address_space(1))) unsigned*)g,
                                   (__attribute__((address_space(3))) unsigned*)l, 16, 0, 0);
}

// ---------------- convert x fp32 -> bf16, 8 elems/thread ----------------
__global__ __launch_bounds__(256) void k_cvt(const float* __restrict__ x,
                                             unsigned short* __restrict__ xb) {
  int i = blockIdx.x * 256 + threadIdx.x;
  const float4* s = (const float4*)x;
  float4 a = s[2 * i], b = s[2 * i + 1];
  u16x8 o;
  o[0] = f2bf(a.x); o[1] = f2bf(a.y); o[2] = f2bf(a.z); o[3] = f2bf(a.w);
  o[4] = f2bf(b.x); o[5] = f2bf(b.y); o[6] = f2bf(b.z); o[7] = f2bf(b.w);
  *(u16x8*)(xb + 8 * (size_t)i) = o;
}

// ------------- transpose+convert weight [K][N] f32 -> [N][K] bf16 -------------
__global__ __launch_bounds__(256) void k_wT(const float* __restrict__ w,
                                            unsigned short* __restrict__ wT,
                                            int Nn, int Kk) {
  __shared__ float tile[32][33];
  const int k0 = blockIdx.x * 32, n0 = blockIdx.y * 32;
  const int t = threadIdx.x;
  const int i = t >> 3, j = (t & 7) * 4;
  float4 v = *(const float4*)(w + (size_t)(k0 + i) * Nn + n0 + j);
  tile[i][j] = v.x; tile[i][j + 1] = v.y; tile[i][j + 2] = v.z; tile[i][j + 3] = v.w;
  __syncthreads();
  const int n = i, k4 = j;
  u16x4 o;
  o[0] = f2bf(tile[k4 + 0][n]); o[1] = f2bf(tile[k4 + 1][n]);
  o[2] = f2bf(tile[k4 + 2][n]); o[3] = f2bf(tile[k4 + 3][n]);
  *(u16x4*)(wT + (size_t)(n0 + n) * Kk + k0 + k4) = o;
}

// ---------------- GEMM: C[M,Nx] = A[M,1024] @ Bt[Nx,1024]^T + bias ----------------
// 128x128 tile, BK=64, row-XOR-swizzled LDS.  XCD band mapping: each XCD owns an
// 8-M-tile band x all N (A band 2MB L2-resident; B streams once).  Requires
// gridDim.x % 8 == 0 and M-tiles == 64.
// EPI 0: fp32 row-major out.  EPI 1: scatter to Q/K bf16 (scaled) + V transposed.
template <int EPI>
__global__ __launch_bounds__(256) void k_gemm(const unsigned short* __restrict__ A,
                                              const unsigned short* __restrict__ Bt,
                                              const float* __restrict__ bias, int Nx,
                                              int MT,
                                              float* __restrict__ outF,
                                              unsigned short* __restrict__ Qb,
                                              unsigned short* __restrict__ Kb,
                                              unsigned short* __restrict__ Vb) {
  __shared__ __attribute__((aligned(16))) unsigned short As[128 * 64];
  __shared__ __attribute__((aligned(16))) unsigned short Bs[128 * 64];
  const int t = threadIdx.x;
  const int jj = blockIdx.x >> 3;
  const int brow = ((blockIdx.x & 7) * 8 + (jj & 7)) * 128;  // 8-M-tile band per XCD
  const int bcol = (jj >> 3) * 128;                          // N advances every 8 blocks
  (void)MT;
  const int lane = t & 63, wid = t >> 6;
  const int wr = (wid >> 1) * 64, wc = (wid & 1) * 64;
  const int g = lane >> 4, qr = lane & 15;
  const f32x4 fzero = {0.f, 0.f, 0.f, 0.f};
  f32x4 acc[4][4];
#pragma unroll
  for (int i = 0; i < 4; ++i)
#pragma unroll
    for (int n = 0; n < 4; ++n) acc[i][n] = fzero;
  // staging: thread t -> tile row (32c + t/8), swizzled k-chunk ((t&7)^(t>>3 &7))*8 elems
  const int strow = t >> 3;                       // 0..31
  const int swz8 = ((t & 7) ^ (strow & 7)) << 3;  // shorts
  const unsigned short* Ag = A + (size_t)(brow + strow) * 1024 + swz8;
  const unsigned short* Bg = Bt + (size_t)(bcol + strow) * 1024 + swz8;
  unsigned short* Asl = As + t * 8;
  unsigned short* Bsl = Bs + t * 8;
  for (int kt = 0; kt < 16; ++kt) {
    const int k0 = kt * 64;
    gl_lds16(Ag + k0, Asl);
    gl_lds16(Ag + 32 * 1024 + k0, Asl + 2048);
    gl_lds16(Ag + 64 * 1024 + k0, Asl + 4096);
    gl_lds16(Ag + 96 * 1024 + k0, Asl + 6144);
    gl_lds16(Bg + k0, Bsl);
    gl_lds16(Bg + 32 * 1024 + k0, Bsl + 2048);
    gl_lds16(Bg + 64 * 1024 + k0, Bsl + 4096);
    gl_lds16(Bg + 96 * 1024 + k0, Bsl + 6144);
    __syncthreads();
    // khalf = 0
    {
      bf16x8 a[4], b[4];
#pragma unroll
      for (int i = 0; i < 4; ++i) {
        const int r = wr + i * 16 + qr;
        a[i] = *(const bf16x8*)&As[r * 64 + ((g ^ (r & 7)) << 3)];
      }
#pragma unroll
      for (int n = 0; n < 4; ++n) {
        const int r = wc + n * 16 + qr;
        b[n] = *(const bf16x8*)&Bs[r * 64 + ((g ^ (r & 7)) << 3)];
      }
#pragma unroll
      for (int i = 0; i < 4; ++i)
#pragma unroll
        for (int n = 0; n < 4; ++n)
          acc[i][n] = __builtin_amdgcn_mfma_f32_16x16x32_bf16(a[i], b[n], acc[i][n], 0, 0, 0);
    }
    // khalf = 1 (k elems +32 -> chunk index +4)
    {
      bf16x8 a[4], b[4];
#pragma unroll
      for (int i = 0; i < 4; ++i) {
        const int r = wr + i * 16 + qr;
        a[i] = *(const bf16x8*)&As[r * 64 + (((4 + g) ^ (r & 7)) << 3)];
      }
#pragma unroll
      for (int n = 0; n < 4; ++n) {
        const int r = wc + n * 16 + qr;
        b[n] = *(const bf16x8*)&Bs[r * 64 + (((4 + g) ^ (r & 7)) << 3)];
      }
#pragma unroll
      for (int i = 0; i < 4; ++i)
#pragma unroll
        for (int n = 0; n < 4; ++n)
          acc[i][n] = __builtin_amdgcn_mfma_f32_16x16x32_bf16(a[i], b[n], acc[i][n], 0, 0, 0);
    }
    __syncthreads();
  }
#pragma unroll
  for (int i = 0; i < 4; ++i) {
#pragma unroll
    for (int n = 0; n < 4; ++n) {
      const int col = bcol + wc + n * 16 + qr;
      const float bv = bias[col];
      float v4[4];
#pragma unroll
      for (int r = 0; r < 4; ++r) v4[r] = acc[i][n][r] + bv;
      const int row0 = brow + wr + i * 16 + g * 4;
      if constexpr (EPI == 0) {
#pragma unroll
        for (int r = 0; r < 4; ++r) outF[(size_t)(row0 + r) * Nx + col] = v4[r];
      } else {
        const int bb = row0 >> 11, tkn0 = row0 & 2047;
        const unsigned c = (unsigned)col;
        const unsigned h = c / 192u;
        const unsigned rem = c - h * 192u;
        const unsigned which = rem >> 6, d = rem & 63u;
        if (which == 2u) {  // V transposed [bh][d][tkn]: 4 consecutive tokens -> 8B store
          u16x4 pk;
#pragma unroll
          for (int r = 0; r < 4; ++r) pk[r] = f2bf(v4[r]);
          *(u16x4*)&Vb[(size_t)(((unsigned)bb * 16u + h) * 64u + d) * 2048u + (unsigned)tkn0] = pk;
        } else {
          // Q gets extra log2e fold (softmax computed in exp2 domain)
          const float sc = (which == 0u) ? (0.35355339059327373f * 1.4426950408889634f)
                                         : 0.35355339059327373f;
          unsigned short* dst = (which == 0u) ? Qb : Kb;
#pragma unroll
          for (int r = 0; r < 4; ++r)
            dst[(size_t)(((unsigned)bb * 16u + h) * 2048u + (unsigned)(tkn0 + r)) * 64u + d] =
                f2bf(v4[r] * sc);
        }
      }
    }
  }
}

// -------- flash attention: 8 waves x 32 q-rows (2 groups), KVBLK=64, LDS dbuf --------
// No-max softmax (exp2 domain; |S_log2| << 126 always for sane inputs), O^T accum.
// (Verified round-6/round-9 kernel, restored byte-identical.)
__global__ __launch_bounds__(512, 4) void k_attn(const unsigned short* __restrict__ Qb,
                                                 const unsigned short* __restrict__ Kb,
                                                 const unsigned short* __restrict__ Vt,
                                                 unsigned short* __restrict__ Ao) {
  __shared__ __attribute__((aligned(16))) unsigned short Kl[2][64][64];
  __shared__ __attribute__((aligned(16))) unsigned short Vl[2][64][64];
  __shared__ __attribute__((aligned(16))) unsigned short Pl[8][2][16][72];
  const int bid = blockIdx.x;
  const int bh = (bid & 7) * 8 + ((bid >> 3) & 7);  // XCD x owns bh 8x..8x+7 (K/V fits its L2)
  const int qt = bid >> 6;                          // 8 q-tiles of 256 rows
  const int t = threadIdx.x, lane = t & 63, w = t >> 6;  // 8 waves
  const int g = lane >> 4, q = lane & 15;
  const int q0 = qt * 256 + w * 32;
  const unsigned short* Qbase = Qb + ((size_t)bh * 2048 + q0) * 64;
  const char* Kg = (const char*)(Kb + (size_t)bh * 2048 * 64);
  const char* Vg = (const char*)(Vt + (size_t)bh * 64 * 2048);
  const int lr = lane >> 3, lc = lane & 7;
  const int swz = (lc ^ lr) << 4;
  const char* Ksrc = Kg + (size_t)(8 * w + lr) * 128 + swz;
  const char* Vsrc = Vg + (size_t)(8 * w + lr) * 4096 + swz;
  unsigned short* Kd[2], *Vd[2];
  Kd[0] = &Kl[0][8 * w][0] + lane * 8;
  Kd[1] = &Kl[1][8 * w][0] + lane * 8;
  Vd[0] = &Vl[0][8 * w][0] + lane * 8;
  Vd[1] = &Vl[1][8 * w][0] + lane * 8;

#define STAGE(buf, it_)                              \
  do {                                               \
    gl_lds16(Ksrc + (size_t)(it_) * 8192, Kd[buf]);  \
    gl_lds16(Vsrc + (size_t)(it_) * 128, Vd[buf]);   \
  } while (0)

  bf16x8 qf[2][2];
#pragma unroll
  for (int G = 0; G < 2; ++G)
#pragma unroll
    for (int h = 0; h < 2; ++h)
      qf[G][h] = *(const bf16x8*)(Qbase + (size_t)(G * 16 + q) * 64 + h * 32 + g * 8);
  const f32x4 fzero = {0.f, 0.f, 0.f, 0.f};
  f32x4 o0[4], o1[4];
#pragma unroll
  for (int i = 0; i < 4; ++i) { o0[i] = fzero; o1[i] = fzero; }
  float l0 = 0.f, l1 = 0.f;  // lane-partial softmax denominators

  STAGE(0, 0);
  __syncthreads();

  for (int it = 0; it < 32; ++it) {
    const int cur = it & 1;
    if (it < 31) STAGE(cur ^ 1, it + 1);
    // ---- QK^T (swapped: A=K rows=keys, B=Q cols=queries), both groups ----
    f32x4 s0[4], s1[4];
    __builtin_amdgcn_s_setprio(1);
#pragma unroll
    for (int kf = 0; kf < 4; ++kf) {
      const int row = kf * 16 + q;
      const char* kp = (const char*)&Kl[cur][row][0];
      const int sw = (row & 7) << 4;
      bf16x8 kaL = *(const bf16x8*)(kp + ((g * 16) ^ sw));
      bf16x8 kaH = *(const bf16x8*)(kp + ((64 + g * 16) ^ sw));
      s0[kf] = __builtin_amdgcn_mfma_f32_16x16x32_bf16(kaL, qf[0][0], fzero, 0, 0, 0);
      s0[kf] = __builtin_amdgcn_mfma_f32_16x16x32_bf16(kaH, qf[0][1], s0[kf], 0, 0, 0);
      s1[kf] = __builtin_amdgcn_mfma_f32_16x16x32_bf16(kaL, qf[1][0], fzero, 0, 0, 0);
      s1[kf] = __builtin_amdgcn_mfma_f32_16x16x32_bf16(kaH, qf[1][1], s1[kf], 0, 0, 0);
    }
    __builtin_amdgcn_s_setprio(0);
    // ---- softmax numerators: P = exp2(S), lane-partial l accumulation ----
    {
      unsigned short* Pw = &Pl[w][0][q][0];
#pragma unroll
      for (int kf = 0; kf < 4; ++kf) {
        const float e0 = __builtin_amdgcn_exp2f(s0[kf][0]);
        const float e1 = __builtin_amdgcn_exp2f(s0[kf][1]);
        const float e2 = __builtin_amdgcn_exp2f(s0[kf][2]);
        const float e3 = __builtin_amdgcn_exp2f(s0[kf][3]);
        l0 += (e0 + e1) + (e2 + e3);
        u32x2 pk;
        pk[0] = cvt_pk_bf16(e0, e1);
        pk[1] = cvt_pk_bf16(e2, e3);
        *(u32x2*)(Pw + (8 * kf + 2 * g) * 2) = pk;
      }
    }
    {
      unsigned short* Pw = &Pl[w][1][q][0];
#pragma unroll
      for (int kf = 0; kf < 4; ++kf) {
        const float e0 = __builtin_amdgcn_exp2f(s1[kf][0]);
        const float e1 = __builtin_amdgcn_exp2f(s1[kf][1]);
        const float e2 = __builtin_amdgcn_exp2f(s1[kf][2]);
        const float e3 = __builtin_amdgcn_exp2f(s1[kf][3]);
        l1 += (e0 + e1) + (e2 + e3);
        u32x2 pk;
        pk[0] = cvt_pk_bf16(e0, e1);
        pk[1] = cvt_pk_bf16(e2, e3);
        *(u32x2*)(Pw + (8 * kf + 2 * g) * 2) = pk;
      }
    }
    asm volatile("" ::: "memory");
    // ---- PV, O^T accumulation: D[row=d][col=query] (query lane-local) ----
    const bf16x8 pa00 = *(const bf16x8*)&Pl[w][0][q][g * 8];
    const bf16x8 pa01 = *(const bf16x8*)&Pl[w][0][q][32 + g * 8];
    const bf16x8 pa10 = *(const bf16x8*)&Pl[w][1][q][g * 8];
    const bf16x8 pa11 = *(const bf16x8*)&Pl[w][1][q][32 + g * 8];
    __builtin_amdgcn_s_setprio(1);
#pragma unroll
    for (int dblk = 0; dblk < 4; ++dblk) {
      const int row = dblk * 16 + q;
      const char* vp = (const char*)&Vl[cur][row][0];
      const int sw = (row & 7) << 4;
      bf16x8 vL = *(const bf16x8*)(vp + ((g * 16) ^ sw));
      bf16x8 vH = *(const bf16x8*)(vp + ((64 + g * 16) ^ sw));
      o0[dblk] = __builtin_amdgcn_mfma_f32_16x16x32_bf16(vL, pa00, o0[dblk], 0, 0, 0);
      o0[dblk] = __builtin_amdgcn_mfma_f32_16x16x32_bf16(vH, pa01, o0[dblk], 0, 0, 0);
      o1[dblk] = __builtin_amdgcn_mfma_f32_16x16x32_bf16(vL, pa10, o1[dblk], 0, 0, 0);
      o1[dblk] = __builtin_amdgcn_mfma_f32_16x16x32_bf16(vH, pa11, o1[dblk], 0, 0, 0);
    }
    __builtin_amdgcn_s_setprio(0);
    __syncthreads();
  }
#undef STAGE
  // finalize l (one cross-lane reduce over g), normalize, write O^T
  l0 += __shfl_xor(l0, 16); l0 += __shfl_xor(l0, 32);
  l1 += __shfl_xor(l1, 16); l1 += __shfl_xor(l1, 32);
  const float li0 = 1.0f / l0, li1 = 1.0f / l1;
  const int bb = bh >> 4, hh = bh & 15;
  {
    unsigned short* ob = Ao + ((size_t)bb * 2048 + q0 + q) * 1024 + hh * 64 + 4 * g;
#pragma unroll
    for (int dblk = 0; dblk < 4; ++dblk) {
      u16x4 pk;
#pragma unroll
      for (int r = 0; r < 4; ++r) pk[r] = f2bf(o0[dblk][r] * li0);
      *(u16x4*)(ob + dblk * 16) = pk;
    }
  }
  {
    unsigned short* ob = Ao + ((size_t)bb * 2048 + q0 + 16 + q) * 1024 + hh * 64 + 4 * g;
#pragma unroll
    for (int dblk = 0; dblk < 4; ++dblk) {
      u16x4 pk;
#pragma unroll
      for (int r = 0; r < 4; ++r) pk[r] = f2bf(o1[dblk][r] * li1);
      *(u16x4*)(ob + dblk * 16) = pk;
    }
  }
}

extern "C" void kernel_launch(void* const* d_in, const int* in_sizes, int n_in,
                              void* d_out, int out_size, void* d_ws, size_t ws_size,
                              hipStream_t stream) {
  const float* x = (const float*)d_in[0];
  const float* w_qkv = (const float*)d_in[1];
  const float* b_qkv = (const float*)d_in[2];
  const float* w_proj = (const float*)d_in[3];
  const float* b_proj = (const float*)d_in[4];
  float* out = (float*)d_out;
  char* ws = (char*)d_ws;
  unsigned short* xb = (unsigned short*)(ws);                  // 16 MB  [8192,1024] bf16
  unsigned short* wqkvT = (unsigned short*)(ws + 16777216);    // 6 MB   [3072,1024]
  unsigned short* wprojT = (unsigned short*)(ws + 23068672);   // 2 MB   [1024,1024]
  unsigned short* Qb = (unsigned short*)(ws + 25165824);       // 16 MB  [bh][2048][64] (log2e folded)
  unsigned short* Kb = (unsigned short*)(ws + 41943040);       // 16 MB  [bh][2048][64]
  unsigned short* Vt = (unsigned short*)(ws + 58720256);       // 16 MB  [bh][64][2048]
  unsigned short* Ao = xb;  // reuse (xb dead after GEMM1)

  hipLaunchKernelGGL(k_cvt, dim3(4096), dim3(256), 0, stream, x, xb);
  hipLaunchKernelGGL(k_wT, dim3(32, 96), dim3(256), 0, stream, w_qkv, wqkvT, 3072, 1024);
  hipLaunchKernelGGL(k_wT, dim3(32, 32), dim3(256), 0, stream, w_proj, wprojT, 1024, 1024);
  hipLaunchKernelGGL((k_gemm<1>), dim3(1536), dim3(256), 0, stream,
                     xb, wqkvT, b_qkv, 3072, 64, (float*)nullptr, Qb, Kb, Vt);
  hipLaunchKernelGGL(k_attn, dim3(512), dim3(512), 0, stream, Qb, Kb, Vt, Ao);
  hipLaunchKernelGGL((k_gemm<0>), dim3(512), dim3(256), 0, stream,
                     Ao, wprojT, b_proj, 1024, 64, out,
                     (unsigned short*)nullptr, (unsigned short*)nullptr, (unsigned short*)nullptr);
}

// Round 12
// 178.524 us; speedup vs baseline: 1.0944x; 1.0028x over previous
//
#include <hip/hip_runtime.h>

typedef __attribute__((ext_vector_type(8))) short bf16x8;   // MFMA A/B frag (8 bf16)
typedef __attribute__((ext_vector_type(4))) float f32x4;    // MFMA C/D frag
typedef __attribute__((ext_vector_type(8))) unsigned short u16x8;
typedef __attribute__((ext_vector_type(4))) unsigned short u16x4;
typedef __attribute__((ext_vector_type(2))) unsigned u32x2;

__device__ __forceinline__ unsigned short f2bf(float f) {
  unsigned u = __builtin_bit_cast(unsigned, f);
  return (unsigned short)((u + 0x7fffu + ((u >> 16) & 1u)) >> 16);
}

__device__ __forceinline__ unsigned cvt_pk_bf16(float lo, float hi) {
  unsigned r;
  asm("v_cvt_pk_bf16_f32 %0, %1, %2" : "=v"(r) : "v"(lo), "v"(hi));
  return r;
}

__device__ __forceinline__ void gl_lds16(const void* g, void* l) {
  __builtin_amdgcn_global_load_lds((const __attribute__((address_space(1))) unsigned*)g,
                                   (__attribute__((address_space(3))) unsigned*)l, 16, 0, 0);
}

// ---------------- merged prep: x->bf16 convert + both weight transposes ----------------
__global__ __launch_bounds__(256) void k_prep(const float* __restrict__ x,
                                              unsigned short* __restrict__ xb,
                                              const float* __restrict__ wq,
                                              unsigned short* __restrict__ wqT,
                                              const float* __restrict__ wp,
                                              unsigned short* __restrict__ wpT) {
  __shared__ float tile[32][33];
  const int bx = blockIdx.x;
  const int t = threadIdx.x;
  if (bx < 4096) {  // convert x fp32 -> bf16, 8 elems/thread
    const int i = bx * 256 + t;
    const float4* s = (const float4*)x;
    float4 a = s[2 * i], b = s[2 * i + 1];
    u16x8 o;
    o[0] = f2bf(a.x); o[1] = f2bf(a.y); o[2] = f2bf(a.z); o[3] = f2bf(a.w);
    o[4] = f2bf(b.x); o[5] = f2bf(b.y); o[6] = f2bf(b.z); o[7] = f2bf(b.w);
    *(u16x8*)(xb + 8 * (size_t)i) = o;
    return;
  }
  // weight transpose+convert [K][N] f32 -> [N][K] bf16
  const int b = bx - 4096;
  const float* w;
  unsigned short* wT;
  int Nn, bb;
  if (b < 3072) { w = wq; wT = wqT; Nn = 3072; bb = b; }
  else          { w = wp; wT = wpT; Nn = 1024; bb = b - 3072; }
  const int k0 = (bb & 31) * 32, n0 = (bb >> 5) * 32;
  const int i = t >> 3, j = (t & 7) * 4;
  float4 v = *(const float4*)(w + (size_t)(k0 + i) * Nn + n0 + j);
  tile[i][j] = v.x; tile[i][j + 1] = v.y; tile[i][j + 2] = v.z; tile[i][j + 3] = v.w;
  __syncthreads();
  const int n = i, k4 = j;
  u16x4 o;
  o[0] = f2bf(tile[k4 + 0][n]); o[1] = f2bf(tile[k4 + 1][n]);
  o[2] = f2bf(tile[k4 + 2][n]); o[3] = f2bf(tile[k4 + 3][n]);
  *(u16x4*)(wT + (size_t)(n0 + n) * 1024 + k0 + k4) = o;
}

// ---------------- GEMM: C[M,Nx] = A[M,1024] @ Bt[Nx,1024]^T + bias ----------------
// 128x128 tile, BK=32, 3-slot LDS ring: stage tile kt+2 while computing kt; one raw
// s_barrier/iter with COUNTED s_waitcnt vmcnt(4) (never drains the pipe to 0 except
// the final peel).  Row-XOR swizzle (chunk c stores global chunk c^(row&3); read at
// g^(r&3)).  XCD band map: each XCD owns an 8-M-tile band x all N.
// EPI 0: fp32 row-major out.  EPI 1: scatter to Q/K bf16 (scaled) + V transposed.
template <int EPI>
__global__ __launch_bounds__(256) void k_gemm(const unsigned short* __restrict__ A,
                                              const unsigned short* __restrict__ Bt,
                                              const float* __restrict__ bias, int Nx,
                                              float* __restrict__ outF,
                                              unsigned short* __restrict__ Qb,
                                              unsigned short* __restrict__ Kb,
                                              unsigned short* __restrict__ Vb) {
  __shared__ __attribute__((aligned(16))) unsigned short As[3][128 * 32];
  __shared__ __attribute__((aligned(16))) unsigned short Bs[3][128 * 32];
  const int t = threadIdx.x;
  const int jj = blockIdx.x >> 3;
  const int brow = ((blockIdx.x & 7) * 8 + (jj & 7)) * 128;  // 8-M-tile band per XCD
  const int bcol = (jj >> 3) * 128;
  const int lane = t & 63, wid = t >> 6;
  const int wr = (wid >> 1) * 64, wc = (wid & 1) * 64;
  const int g = lane >> 4, qr = lane & 15;
  const f32x4 fzero = {0.f, 0.f, 0.f, 0.f};
  f32x4 acc[4][4];
#pragma unroll
  for (int i = 0; i < 4; ++i)
#pragma unroll
    for (int n = 0; n < 4; ++n) acc[i][n] = fzero;
  // staging: thread t -> rows t/4 and t/4+64, chunk t&3; source chunk pre-swizzled
  const int srow = t >> 2;                 // 0..63
  const int sg = (t & 3) ^ (srow & 3);     // (row+64)&3 == row&3, so same for call1
  const unsigned short* Ag0 = A + (size_t)(brow + srow) * 1024 + sg * 8;
  const unsigned short* Bg0 = Bt + (size_t)(bcol + srow) * 1024 + sg * 8;

#define STAGE(s_, kt_)                                        \
  do {                                                        \
    const int koff = (kt_) * 32;                              \
    gl_lds16(Ag0 + koff, &As[s_][t * 8]);                     \
    gl_lds16(Ag0 + 64 * 1024 + koff, &As[s_][2048 + t * 8]);  \
    gl_lds16(Bg0 + koff, &Bs[s_][t * 8]);                     \
    gl_lds16(Bg0 + 64 * 1024 + koff, &Bs[s_][2048 + t * 8]);  \
  } while (0)

  STAGE(0, 0);
  STAGE(1, 1);
  for (int kt = 0; kt < 32; ++kt) {
    const int s = kt % 3;
    if (kt < 31) {
      asm volatile("s_waitcnt vmcnt(4)" ::: "memory");  // tile kt landed; kt+1 in flight
    } else {
      asm volatile("s_waitcnt vmcnt(0)" ::: "memory");  // final tile: full drain
    }
    __builtin_amdgcn_s_barrier();
    __builtin_amdgcn_sched_barrier(0);
    bf16x8 a[4], b[4];
#pragma unroll
    for (int i = 0; i < 4; ++i) {
      const int r = wr + i * 16 + qr;
      a[i] = *(const bf16x8*)&As[s][r * 32 + ((g ^ (r & 3)) << 3)];
    }
#pragma unroll
    for (int n = 0; n < 4; ++n) {
      const int r = wc + n * 16 + qr;
      b[n] = *(const bf16x8*)&Bs[s][r * 32 + ((g ^ (r & 3)) << 3)];
    }
    __builtin_amdgcn_s_setprio(1);
#pragma unroll
    for (int i = 0; i < 4; ++i)
#pragma unroll
      for (int n = 0; n < 4; ++n)
        acc[i][n] = __builtin_amdgcn_mfma_f32_16x16x32_bf16(a[i], b[n], acc[i][n], 0, 0, 0);
    __builtin_amdgcn_s_setprio(0);
    if (kt < 30) STAGE((kt + 2) % 3, kt + 2);
  }
#undef STAGE
#pragma unroll
  for (int i = 0; i < 4; ++i) {
#pragma unroll
    for (int n = 0; n < 4; ++n) {
      const int col = bcol + wc + n * 16 + qr;
      const float bv = bias[col];
      float v4[4];
#pragma unroll
      for (int r = 0; r < 4; ++r) v4[r] = acc[i][n][r] + bv;
      const int row0 = brow + wr + i * 16 + g * 4;
      if constexpr (EPI == 0) {
#pragma unroll
        for (int r = 0; r < 4; ++r) outF[(size_t)(row0 + r) * Nx + col] = v4[r];
      } else {
        const int bb = row0 >> 11, tkn0 = row0 & 2047;
        const unsigned c = (unsigned)col;
        const unsigned h = c / 192u;
        const unsigned rem = c - h * 192u;
        const unsigned which = rem >> 6, d = rem & 63u;
        if (which == 2u) {  // V transposed [bh][d][tkn]: 4 consecutive tokens -> 8B store
          u16x4 pk;
#pragma unroll
          for (int r = 0; r < 4; ++r) pk[r] = f2bf(v4[r]);
          *(u16x4*)&Vb[(size_t)(((unsigned)bb * 16u + h) * 64u + d) * 2048u + (unsigned)tkn0] = pk;
        } else {
          // Q gets extra log2e fold (softmax computed in exp2 domain)
          const float sc = (which == 0u) ? (0.35355339059327373f * 1.4426950408889634f)
                                         : 0.35355339059327373f;
          unsigned short* dst = (which == 0u) ? Qb : Kb;
#pragma unroll
          for (int r = 0; r < 4; ++r)
            dst[(size_t)(((unsigned)bb * 16u + h) * 2048u + (unsigned)(tkn0 + r)) * 64u + d] =
                f2bf(v4[r] * sc);
        }
      }
    }
  }
}

// -------- flash attention: 8 waves x 32 q-rows (2 groups), KVBLK=64, LDS dbuf --------
// No-max softmax (exp2 domain; |S_log2| << 126 always for sane inputs), O^T accum.
// (Verified round-6/round-9/round-11 kernel, byte-identical.)
__global__ __launch_bounds__(512, 4) void k_attn(const unsigned short* __restrict__ Qb,
                                                 const unsigned short* __restrict__ Kb,
                                                 const unsigned short* __restrict__ Vt,
                                                 unsigned short* __restrict__ Ao) {
  __shared__ __attribute__((aligned(16))) unsigned short Kl[2][64][64];
  __shared__ __attribute__((aligned(16))) unsigned short Vl[2][64][64];
  __shared__ __attribute__((aligned(16))) unsigned short Pl[8][2][16][72];
  const int bid = blockIdx.x;
  const int bh = (bid & 7) * 8 + ((bid >> 3) & 7);  // XCD x owns bh 8x..8x+7 (K/V fits its L2)
  const int qt = bid >> 6;                          // 8 q-tiles of 256 rows
  const int t = threadIdx.x, lane = t & 63, w = t >> 6;  // 8 waves
  const int g = lane >> 4, q = lane & 15;
  const int q0 = qt * 256 + w * 32;
  const unsigned short* Qbase = Qb + ((size_t)bh * 2048 + q0) * 64;
  const char* Kg = (const char*)(Kb + (size_t)bh * 2048 * 64);
  const char* Vg = (const char*)(Vt + (size_t)bh * 64 * 2048);
  const int lr = lane >> 3, lc = lane & 7;
  const int swz = (lc ^ lr) << 4;
  const char* Ksrc = Kg + (size_t)(8 * w + lr) * 128 + swz;
  const char* Vsrc = Vg + (size_t)(8 * w + lr) * 4096 + swz;
  unsigned short* Kd[2], *Vd[2];
  Kd[0] = &Kl[0][8 * w][0] + lane * 8;
  Kd[1] = &Kl[1][8 * w][0] + lane * 8;
  Vd[0] = &Vl[0][8 * w][0] + lane * 8;
  Vd[1] = &Vl[1][8 * w][0] + lane * 8;

#define STAGE(buf, it_)                              \
  do {                                               \
    gl_lds16(Ksrc + (size_t)(it_) * 8192, Kd[buf]);  \
    gl_lds16(Vsrc + (size_t)(it_) * 128, Vd[buf]);   \
  } while (0)

  bf16x8 qf[2][2];
#pragma unroll
  for (int G = 0; G < 2; ++G)
#pragma unroll
    for (int h = 0; h < 2; ++h)
      qf[G][h] = *(const bf16x8*)(Qbase + (size_t)(G * 16 + q) * 64 + h * 32 + g * 8);
  const f32x4 fzero = {0.f, 0.f, 0.f, 0.f};
  f32x4 o0[4], o1[4];
#pragma unroll
  for (int i = 0; i < 4; ++i) { o0[i] = fzero; o1[i] = fzero; }
  float l0 = 0.f, l1 = 0.f;  // lane-partial softmax denominators

  STAGE(0, 0);
  __syncthreads();

  for (int it = 0; it < 32; ++it) {
    const int cur = it & 1;
    if (it < 31) STAGE(cur ^ 1, it + 1);
    // ---- QK^T (swapped: A=K rows=keys, B=Q cols=queries), both groups ----
    f32x4 s0[4], s1[4];
    __builtin_amdgcn_s_setprio(1);
#pragma unroll
    for (int kf = 0; kf < 4; ++kf) {
      const int row = kf * 16 + q;
      const char* kp = (const char*)&Kl[cur][row][0];
      const int sw = (row & 7) << 4;
      bf16x8 kaL = *(const bf16x8*)(kp + ((g * 16) ^ sw));
      bf16x8 kaH = *(const bf16x8*)(kp + ((64 + g * 16) ^ sw));
      s0[kf] = __builtin_amdgcn_mfma_f32_16x16x32_bf16(kaL, qf[0][0], fzero, 0, 0, 0);
      s0[kf] = __builtin_amdgcn_mfma_f32_16x16x32_bf16(kaH, qf[0][1], s0[kf], 0, 0, 0);
      s1[kf] = __builtin_amdgcn_mfma_f32_16x16x32_bf16(kaL, qf[1][0], fzero, 0, 0, 0);
      s1[kf] = __builtin_amdgcn_mfma_f32_16x16x32_bf16(kaH, qf[1][1], s1[kf], 0, 0, 0);
    }
    __builtin_amdgcn_s_setprio(0);
    // ---- softmax numerators: P = exp2(S), lane-partial l accumulation ----
    {
      unsigned short* Pw = &Pl[w][0][q][0];
#pragma unroll
      for (int kf = 0; kf < 4; ++kf) {
        const float e0 = __builtin_amdgcn_exp2f(s0[kf][0]);
        const float e1 = __builtin_amdgcn_exp2f(s0[kf][1]);
        const float e2 = __builtin_amdgcn_exp2f(s0[kf][2]);
        const float e3 = __builtin_amdgcn_exp2f(s0[kf][3]);
        l0 += (e0 + e1) + (e2 + e3);
        u32x2 pk;
        pk[0] = cvt_pk_bf16(e0, e1);
        pk[1] = cvt_pk_bf16(e2, e3);
        *(u32x2*)(Pw + (8 * kf + 2 * g) * 2) = pk;
      }
    }
    {
      unsigned short* Pw = &Pl[w][1][q][0];
#pragma unroll
      for (int kf = 0; kf < 4; ++kf) {
        const float e0 = __builtin_amdgcn_exp2f(s1[kf][0]);
        const float e1 = __builtin_amdgcn_exp2f(s1[kf][1]);
        const float e2 = __builtin_amdgcn_exp2f(s1[kf][2]);
        const float e3 = __builtin_amdgcn_exp2f(s1[kf][3]);
        l1 += (e0 + e1) + (e2 + e3);
        u32x2 pk;
        pk[0] = cvt_pk_bf16(e0, e1);
        pk[1] = cvt_pk_bf16(e2, e3);
        *(u32x2*)(Pw + (8 * kf + 2 * g) * 2) = pk;
      }
    }
    asm volatile("" ::: "memory");
    // ---- PV, O^T accumulation: D[row=d][col=query] (query lane-local) ----
    const bf16x8 pa00 = *(const bf16x8*)&Pl[w][0][q][g * 8];
    const bf16x8 pa01 = *(const bf16x8*)&Pl[w][0][q][32 + g * 8];
    const bf16x8 pa10 = *(const bf16x8*)&Pl[w][1][q][g * 8];
    const bf16x8 pa11 = *(const bf16x8*)&Pl[w][1][q][32 + g * 8];
    __builtin_amdgcn_s_setprio(1);
#pragma unroll
    for (int dblk = 0; dblk < 4; ++dblk) {
      const int row = dblk * 16 + q;
      const char* vp = (const char*)&Vl[cur][row][0];
      const int sw = (row & 7) << 4;
      bf16x8 vL = *(const bf16x8*)(vp + ((g * 16) ^ sw));
      bf16x8 vH = *(const bf16x8*)(vp + ((64 + g * 16) ^ sw));
      o0[dblk] = __builtin_amdgcn_mfma_f32_16x16x32_bf16(vL, pa00, o0[dblk], 0, 0, 0);
      o0[dblk] = __builtin_amdgcn_mfma_f32_16x16x32_bf16(vH, pa01, o0[dblk], 0, 0, 0);
      o1[dblk] = __builtin_amdgcn_mfma_f32_16x16x32_bf16(vL, pa10, o1[dblk], 0, 0, 0);
      o1[dblk] = __builtin_amdgcn_mfma_f32_16x16x32_bf16(vH, pa11, o1[dblk], 0, 0, 0);
    }
    __builtin_amdgcn_s_setprio(0);
    __syncthreads();
  }
#undef STAGE
  // finalize l (one cross-lane reduce over g), normalize, write O^T
  l0 += __shfl_xor(l0, 16); l0 += __shfl_xor(l0, 32);
  l1 += __shfl_xor(l1, 16); l1 += __shfl_xor(l1, 32);
  const float li0 = 1.0f / l0, li1 = 1.0f / l1;
  const int bb = bh >> 4, hh = bh & 15;
  {
    unsigned short* ob = Ao + ((size_t)bb * 2048 + q0 + q) * 1024 + hh * 64 + 4 * g;
#pragma unroll
    for (int dblk = 0; dblk < 4; ++dblk) {
      u16x4 pk;
#pragma unroll
      for (int r = 0; r < 4; ++r) pk[r] = f2bf(o0[dblk][r] * li0);
      *(u16x4*)(ob + dblk * 16) = pk;
    }
  }
  {
    unsigned short* ob = Ao + ((size_t)bb * 2048 + q0 + 16 + q) * 1024 + hh * 64 + 4 * g;
#pragma unroll
    for (int dblk = 0; dblk < 4; ++dblk) {
      u16x4 pk;
#pragma unroll
      for (int r = 0; r < 4; ++r) pk[r] = f2bf(o1[dblk][r] * li1);
      *(u16x4*)(ob + dblk * 16) = pk;
    }
  }
}

extern "C" void kernel_launch(void* const* d_in, const int* in_sizes, int n_in,
                              void* d_out, int out_size, void* d_ws, size_t ws_size,
                              hipStream_t stream) {
  const float* x = (const float*)d_in[0];
  const float* w_qkv = (const float*)d_in[1];
  const float* b_qkv = (const float*)d_in[2];
  const float* w_proj = (const float*)d_in[3];
  const float* b_proj = (const float*)d_in[4];
  float* out = (float*)d_out;
  char* ws = (char*)d_ws;
  unsigned short* xb = (unsigned short*)(ws);                  // 16 MB  [8192,1024] bf16
  unsigned short* wqkvT = (unsigned short*)(ws + 16777216);    // 6 MB   [3072,1024]
  unsigned short* wprojT = (unsigned short*)(ws + 23068672);   // 2 MB   [1024,1024]
  unsigned short* Qb = (unsigned short*)(ws + 25165824);       // 16 MB  [bh][2048][64] (log2e folded)
  unsigned short* Kb = (unsigned short*)(ws + 41943040);       // 16 MB  [bh][2048][64]
  unsigned short* Vt = (unsigned short*)(ws + 58720256);       // 16 MB  [bh][64][2048]
  unsigned short* Ao = xb;  // reuse (xb dead after GEMM1)

  hipLaunchKernelGGL(k_prep, dim3(8192), dim3(256), 0, stream,
                     x, xb, w_qkv, wqkvT, w_proj, wprojT);
  hipLaunchKernelGGL((k_gemm<1>), dim3(1536), dim3(256), 0, stream,
                     xb, wqkvT, b_qkv, 3072, (float*)nullptr, Qb, Kb, Vt);
  hipLaunchKernelGGL(k_attn, dim3(512), dim3(512), 0, stream, Qb, Kb, Vt, Ao);
  hipLaunchKernelGGL((k_gemm<0>), dim3(512), dim3(256), 0, stream,
                     Ao, wprojT, b_proj, 1024, out,
                     (unsigned short*)nullptr, (unsigned short*)nullptr, (unsigned short*)nullptr);
}

// Round 14
// 177.751 us; speedup vs baseline: 1.0992x; 1.0043x over previous
//
#include <hip/hip_runtime.h>

typedef __attribute__((ext_vector_type(8))) short bf16x8;   // MFMA A/B frag (8 bf16)
typedef __attribute__((ext_vector_type(4))) float f32x4;    // MFMA C/D frag
typedef __attribute__((ext_vector_type(8))) unsigned short u16x8;
typedef __attribute__((ext_vector_type(4))) unsigned short u16x4;
typedef __attribute__((ext_vector_type(2))) unsigned u32x2;

__device__ __forceinline__ unsigned short f2bf(float f) {
  unsigned u = __builtin_bit_cast(unsigned, f);
  return (unsigned short)((u + 0x7fffu + ((u >> 16) & 1u)) >> 16);
}

__device__ __forceinline__ unsigned cvt_pk_bf16(float lo, float hi) {
  unsigned r;
  asm("v_cvt_pk_bf16_f32 %0, %1, %2" : "=v"(r) : "v"(lo), "v"(hi));
  return r;
}

__device__ __forceinline__ void gl_lds16(const void* g, void* l) {
  __builtin_amdgcn_global_load_lds((const __attribute__((address_space(1))) unsigned*)g,
                                   (__attribute__((address_space(3))) unsigned*)l, 16, 0, 0);
}

// ---------------- merged prep: x->bf16 convert + both weight transposes ----------------
__global__ __launch_bounds__(256) void k_prep(const float* __restrict__ x,
                                              unsigned short* __restrict__ xb,
                                              const float* __restrict__ wq,
                                              unsigned short* __restrict__ wqT,
                                              const float* __restrict__ wp,
                                              unsigned short* __restrict__ wpT) {
  __shared__ float tile[32][33];
  const int bx = blockIdx.x;
  const int t = threadIdx.x;
  if (bx < 4096) {  // convert x fp32 -> bf16, 8 elems/thread
    const int i = bx * 256 + t;
    const float4* s = (const float4*)x;
    float4 a = s[2 * i], b = s[2 * i + 1];
    u16x8 o;
    o[0] = f2bf(a.x); o[1] = f2bf(a.y); o[2] = f2bf(a.z); o[3] = f2bf(a.w);
    o[4] = f2bf(b.x); o[5] = f2bf(b.y); o[6] = f2bf(b.z); o[7] = f2bf(b.w);
    *(u16x8*)(xb + 8 * (size_t)i) = o;
    return;
  }
  // weight transpose+convert [K][N] f32 -> [N][K] bf16
  const int b = bx - 4096;
  const float* w;
  unsigned short* wT;
  int Nn, bb;
  if (b < 3072) { w = wq; wT = wqT; Nn = 3072; bb = b; }
  else          { w = wp; wT = wpT; Nn = 1024; bb = b - 3072; }
  const int k0 = (bb & 31) * 32, n0 = (bb >> 5) * 32;
  const int i = t >> 3, j = (t & 7) * 4;
  float4 v = *(const float4*)(w + (size_t)(k0 + i) * Nn + n0 + j);
  tile[i][j] = v.x; tile[i][j + 1] = v.y; tile[i][j + 2] = v.z; tile[i][j + 3] = v.w;
  __syncthreads();
  const int n = i, k4 = j;
  u16x4 o;
  o[0] = f2bf(tile[k4 + 0][n]); o[1] = f2bf(tile[k4 + 1][n]);
  o[2] = f2bf(tile[k4 + 2][n]); o[3] = f2bf(tile[k4 + 3][n]);
  *(u16x4*)(wT + (size_t)(n0 + n) * 1024 + k0 + k4) = o;
}

// ---------------- GEMM: C[M,Nx] = A[M,1024] @ Bt[Nx,1024]^T + bias ----------------
// 128x128 tile, BK=32, 3-slot LDS ring, counted vmcnt(4), row-XOR swizzle,
// XCD band map (each XCD owns an 8-M-tile band x all N).  (Round-12 verified.)
// EPI 0: fp32 row-major out.  EPI 1: scatter to Q/K bf16 (scaled) + V transposed.
template <int EPI>
__global__ __launch_bounds__(256) void k_gemm(const unsigned short* __restrict__ A,
                                              const unsigned short* __restrict__ Bt,
                                              const float* __restrict__ bias, int Nx,
                                              float* __restrict__ outF,
                                              unsigned short* __restrict__ Qb,
                                              unsigned short* __restrict__ Kb,
                                              unsigned short* __restrict__ Vb) {
  __shared__ __attribute__((aligned(16))) unsigned short As[3][128 * 32];
  __shared__ __attribute__((aligned(16))) unsigned short Bs[3][128 * 32];
  const int t = threadIdx.x;
  const int jj = blockIdx.x >> 3;
  const int brow = ((blockIdx.x & 7) * 8 + (jj & 7)) * 128;  // 8-M-tile band per XCD
  const int bcol = (jj >> 3) * 128;
  const int lane = t & 63, wid = t >> 6;
  const int wr = (wid >> 1) * 64, wc = (wid & 1) * 64;
  const int g = lane >> 4, qr = lane & 15;
  const f32x4 fzero = {0.f, 0.f, 0.f, 0.f};
  f32x4 acc[4][4];
#pragma unroll
  for (int i = 0; i < 4; ++i)
#pragma unroll
    for (int n = 0; n < 4; ++n) acc[i][n] = fzero;
  const int srow = t >> 2;                 // 0..63
  const int sg = (t & 3) ^ (srow & 3);     // pre-swizzled source chunk
  const unsigned short* Ag0 = A + (size_t)(brow + srow) * 1024 + sg * 8;
  const unsigned short* Bg0 = Bt + (size_t)(bcol + srow) * 1024 + sg * 8;

#define STAGE(s_, kt_)                                        \
  do {                                                        \
    const int koff = (kt_) * 32;                              \
    gl_lds16(Ag0 + koff, &As[s_][t * 8]);                     \
    gl_lds16(Ag0 + 64 * 1024 + koff, &As[s_][2048 + t * 8]);  \
    gl_lds16(Bg0 + koff, &Bs[s_][t * 8]);                     \
    gl_lds16(Bg0 + 64 * 1024 + koff, &Bs[s_][2048 + t * 8]);  \
  } while (0)

  STAGE(0, 0);
  STAGE(1, 1);
  for (int kt = 0; kt < 32; ++kt) {
    const int s = kt % 3;
    if (kt < 31) {
      asm volatile("s_waitcnt vmcnt(4)" ::: "memory");
    } else {
      asm volatile("s_waitcnt vmcnt(0)" ::: "memory");
    }
    __builtin_amdgcn_s_barrier();
    __builtin_amdgcn_sched_barrier(0);
    bf16x8 a[4], b[4];
#pragma unroll
    for (int i = 0; i < 4; ++i) {
      const int r = wr + i * 16 + qr;
      a[i] = *(const bf16x8*)&As[s][r * 32 + ((g ^ (r & 3)) << 3)];
    }
#pragma unroll
    for (int n = 0; n < 4; ++n) {
      const int r = wc + n * 16 + qr;
      b[n] = *(const bf16x8*)&Bs[s][r * 32 + ((g ^ (r & 3)) << 3)];
    }
    __builtin_amdgcn_s_setprio(1);
#pragma unroll
    for (int i = 0; i < 4; ++i)
#pragma unroll
      for (int n = 0; n < 4; ++n)
        acc[i][n] = __builtin_amdgcn_mfma_f32_16x16x32_bf16(a[i], b[n], acc[i][n], 0, 0, 0);
    __builtin_amdgcn_s_setprio(0);
    if (kt < 30) STAGE((kt + 2) % 3, kt + 2);
  }
#undef STAGE
#pragma unroll
  for (int i = 0; i < 4; ++i) {
#pragma unroll
    for (int n = 0; n < 4; ++n) {
      const int col = bcol + wc + n * 16 + qr;
      const float bv = bias[col];
      float v4[4];
#pragma unroll
      for (int r = 0; r < 4; ++r) v4[r] = acc[i][n][r] + bv;
      const int row0 = brow + wr + i * 16 + g * 4;
      if constexpr (EPI == 0) {
#pragma unroll
        for (int r = 0; r < 4; ++r) outF[(size_t)(row0 + r) * Nx + col] = v4[r];
      } else {
        const int bb = row0 >> 11, tkn0 = row0 & 2047;
        const unsigned c = (unsigned)col;
        const unsigned h = c / 192u;
        const unsigned rem = c - h * 192u;
        const unsigned which = rem >> 6, d = rem & 63u;
        if (which == 2u) {  // V transposed [bh][d][tkn]: 4 consecutive tokens -> 8B store
          u16x4 pk;
#pragma unroll
          for (int r = 0; r < 4; ++r) pk[r] = f2bf(v4[r]);
          *(u16x4*)&Vb[(size_t)(((unsigned)bb * 16u + h) * 64u + d) * 2048u + (unsigned)tkn0] = pk;
        } else {
          // Q gets extra log2e fold (softmax computed in exp2 domain)
          const float sc = (which == 0u) ? (0.35355339059327373f * 1.4426950408889634f)
                                         : 0.35355339059327373f;
          unsigned short* dst = (which == 0u) ? Qb : Kb;
#pragma unroll
          for (int r = 0; r < 4; ++r)
            dst[(size_t)(((unsigned)bb * 16u + h) * 2048u + (unsigned)(tkn0 + r)) * 64u + d] =
                f2bf(v4[r] * sc);
        }
      }
    }
  }
}

// -------- flash attention: 8 waves x 32 q-rows (2 groups), KVBLK=64 --------
// R12-verified dataflow (K,V LDS-staged; P via LDS bounce; VALU l-sum).  Sync
// upgraded to counted-vmcnt ring: K in 3 slots, V dbuf; per-iter wait vmcnt(1)
// (needed K/V tiles are the oldest in-flight loads) + raw s_barrier.
__global__ __launch_bounds__(512, 4) void k_attn(const unsigned short* __restrict__ Qb,
                                                 const unsigned short* __restrict__ Kb,
                                                 const unsigned short* __restrict__ Vt,
                                                 unsigned short* __restrict__ Ao) {
  __shared__ __attribute__((aligned(16))) unsigned short Kl[3][64][64];
  __shared__ __attribute__((aligned(16))) unsigned short Vl[2][64][64];
  __shared__ __attribute__((aligned(16))) unsigned short Pl[8][2][16][72];
  const int bid = blockIdx.x;
  const int bh = (bid & 7) * 8 + ((bid >> 3) & 7);  // XCD x owns bh 8x..8x+7 (K/V fits its L2)
  const int qt = bid >> 6;                          // 8 q-tiles of 256 rows
  const int t = threadIdx.x, lane = t & 63, w = t >> 6;  // 8 waves
  const int g = lane >> 4, q = lane & 15;
  const int q0 = qt * 256 + w * 32;
  const unsigned short* Qbase = Qb + ((size_t)bh * 2048 + q0) * 64;
  const char* Kg = (const char*)(Kb + (size_t)bh * 2048 * 64);
  const char* Vg = (const char*)(Vt + (size_t)bh * 64 * 2048);
  const int lr = lane >> 3, lc = lane & 7;
  const int swz = (lc ^ lr) << 4;
  const char* Ksrc = Kg + (size_t)(8 * w + lr) * 128 + swz;
  const char* Vsrc = Vg + (size_t)(8 * w + lr) * 4096 + swz;

#define KST(s_, it_) gl_lds16(Ksrc + (size_t)(it_) * 8192, &Kl[s_][8 * w][0] + lane * 8)
#define VST(b_, it_) gl_lds16(Vsrc + (size_t)(it_) * 128, &Vl[b_][8 * w][0] + lane * 8)

  bf16x8 qf[2][2];
#pragma unroll
  for (int G = 0; G < 2; ++G)
#pragma unroll
    for (int h = 0; h < 2; ++h)
      qf[G][h] = *(const bf16x8*)(Qbase + (size_t)(G * 16 + q) * 64 + h * 32 + g * 8);
  const f32x4 fzero = {0.f, 0.f, 0.f, 0.f};
  f32x4 o0[4], o1[4];
#pragma unroll
  for (int i = 0; i < 4; ++i) { o0[i] = fzero; o1[i] = fzero; }
  float l0 = 0.f, l1 = 0.f;  // lane-partial softmax denominators

  // prologue: K0, V0, K1 (oldest-first order matches per-iter vmcnt(1) wait)
  KST(0, 0);
  VST(0, 0);
  KST(1, 1);

  for (int it = 0; it < 32; ++it) {
    const int s = it % 3, vb = it & 1;
    if (it < 31) {
      asm volatile("s_waitcnt vmcnt(1)" ::: "memory");  // K(it),V(it) landed; next may fly
    } else {
      asm volatile("s_waitcnt vmcnt(0)" ::: "memory");
    }
    __builtin_amdgcn_s_barrier();
    __builtin_amdgcn_sched_barrier(0);
    // ---- QK^T (swapped: A=K rows=keys, B=Q cols=queries), both groups ----
    f32x4 s0[4], s1[4];
    __builtin_amdgcn_s_setprio(1);
#pragma unroll
    for (int kf = 0; kf < 4; ++kf) {
      const int row = kf * 16 + q;
      const char* kp = (const char*)&Kl[s][row][0];
      const int sw = (row & 7) << 4;
      bf16x8 kaL = *(const bf16x8*)(kp + ((g * 16) ^ sw));
      bf16x8 kaH = *(const bf16x8*)(kp + ((64 + g * 16) ^ sw));
      s0[kf] = __builtin_amdgcn_mfma_f32_16x16x32_bf16(kaL, qf[0][0], fzero, 0, 0, 0);
      s0[kf] = __builtin_amdgcn_mfma_f32_16x16x32_bf16(kaH, qf[0][1], s0[kf], 0, 0, 0);
      s1[kf] = __builtin_amdgcn_mfma_f32_16x16x32_bf16(kaL, qf[1][0], fzero, 0, 0, 0);
      s1[kf] = __builtin_amdgcn_mfma_f32_16x16x32_bf16(kaH, qf[1][1], s1[kf], 0, 0, 0);
    }
    __builtin_amdgcn_s_setprio(0);
    // ---- softmax numerators: P = exp2(S), lane-partial l accumulation ----
    {
      unsigned short* Pw = &Pl[w][0][q][0];
#pragma unroll
      for (int kf = 0; kf < 4; ++kf) {
        const float e0 = __builtin_amdgcn_exp2f(s0[kf][0]);
        const float e1 = __builtin_amdgcn_exp2f(s0[kf][1]);
        const float e2 = __builtin_amdgcn_exp2f(s0[kf][2]);
        const float e3 = __builtin_amdgcn_exp2f(s0[kf][3]);
        l0 += (e0 + e1) + (e2 + e3);
        u32x2 pk;
        pk[0] = cvt_pk_bf16(e0, e1);
        pk[1] = cvt_pk_bf16(e2, e3);
        *(u32x2*)(Pw + (8 * kf + 2 * g) * 2) = pk;
      }
    }
    {
      unsigned short* Pw = &Pl[w][1][q][0];
#pragma unroll
      for (int kf = 0; kf < 4; ++kf) {
        const float e0 = __builtin_amdgcn_exp2f(s1[kf][0]);
        const float e1 = __builtin_amdgcn_exp2f(s1[kf][1]);
        const float e2 = __builtin_amdgcn_exp2f(s1[kf][2]);
        const float e3 = __builtin_amdgcn_exp2f(s1[kf][3]);
        l1 += (e0 + e1) + (e2 + e3);
        u32x2 pk;
        pk[0] = cvt_pk_bf16(e0, e1);
        pk[1] = cvt_pk_bf16(e2, e3);
        *(u32x2*)(Pw + (8 * kf + 2 * g) * 2) = pk;
      }
    }
    asm volatile("" ::: "memory");
    // ---- PV, O^T accumulation: D[row=d][col=query] (query lane-local) ----
    const bf16x8 pa00 = *(const bf16x8*)&Pl[w][0][q][g * 8];
    const bf16x8 pa01 = *(const bf16x8*)&Pl[w][0][q][32 + g * 8];
    const bf16x8 pa10 = *(const bf16x8*)&Pl[w][1][q][g * 8];
    const bf16x8 pa11 = *(const bf16x8*)&Pl[w][1][q][32 + g * 8];
    __builtin_amdgcn_s_setprio(1);
#pragma unroll
    for (int dblk = 0; dblk < 4; ++dblk) {
      const int row = dblk * 16 + q;
      const char* vp = (const char*)&Vl[vb][row][0];
      const int sw = (row & 7) << 4;
      bf16x8 vL = *(const bf16x8*)(vp + ((g * 16) ^ sw));
      bf16x8 vH = *(const bf16x8*)(vp + ((64 + g * 16) ^ sw));
      o0[dblk] = __builtin_amdgcn_mfma_f32_16x16x32_bf16(vL, pa00, o0[dblk], 0, 0, 0);
      o0[dblk] = __builtin_amdgcn_mfma_f32_16x16x32_bf16(vH, pa01, o0[dblk], 0, 0, 0);
      o1[dblk] = __builtin_amdgcn_mfma_f32_16x16x32_bf16(vL, pa10, o1[dblk], 0, 0, 0);
      o1[dblk] = __builtin_amdgcn_mfma_f32_16x16x32_bf16(vH, pa11, o1[dblk], 0, 0, 0);
    }
    __builtin_amdgcn_s_setprio(0);
    // ---- issue future stages (V first so needed tiles stay oldest in FIFO) ----
    if (it < 31) VST(vb ^ 1, it + 1);
    if (it < 30) KST((it + 2) % 3, it + 2);
  }
#undef KST
#undef VST
  // finalize l (one cross-lane reduce over g), normalize, write O^T
  l0 += __shfl_xor(l0, 16); l0 += __shfl_xor(l0, 32);
  l1 += __shfl_xor(l1, 16); l1 += __shfl_xor(l1, 32);
  const float li0 = 1.0f / l0, li1 = 1.0f / l1;
  const int bb = bh >> 4, hh = bh & 15;
  {
    unsigned short* ob = Ao + ((size_t)bb * 2048 + q0 + q) * 1024 + hh * 64 + 4 * g;
#pragma unroll
    for (int dblk = 0; dblk < 4; ++dblk) {
      u16x4 pk;
#pragma unroll
      for (int r = 0; r < 4; ++r) pk[r] = f2bf(o0[dblk][r] * li0);
      *(u16x4*)(ob + dblk * 16) = pk;
    }
  }
  {
    unsigned short* ob = Ao + ((size_t)bb * 2048 + q0 + 16 + q) * 1024 + hh * 64 + 4 * g;
#pragma unroll
    for (int dblk = 0; dblk < 4; ++dblk) {
      u16x4 pk;
#pragma unroll
      for (int r = 0; r < 4; ++r) pk[r] = f2bf(o1[dblk][r] * li1);
      *(u16x4*)(ob + dblk * 16) = pk;
    }
  }
}

extern "C" void kernel_launch(void* const* d_in, const int* in_sizes, int n_in,
                              void* d_out, int out_size, void* d_ws, size_t ws_size,
                              hipStream_t stream) {
  const float* x = (const float*)d_in[0];
  const float* w_qkv = (const float*)d_in[1];
  const float* b_qkv = (const float*)d_in[2];
  const float* w_proj = (const float*)d_in[3];
  const float* b_proj = (const float*)d_in[4];
  float* out = (float*)d_out;
  char* ws = (char*)d_ws;
  unsigned short* xb = (unsigned short*)(ws);                  // 16 MB  [8192,1024] bf16
  unsigned short* wqkvT = (unsigned short*)(ws + 16777216);    // 6 MB   [3072,1024]
  unsigned short* wprojT = (unsigned short*)(ws + 23068672);   // 2 MB   [1024,1024]
  unsigned short* Qb = (unsigned short*)(ws + 25165824);       // 16 MB  [bh][2048][64] (log2e folded)
  unsigned short* Kb = (unsigned short*)(ws + 41943040);       // 16 MB  [bh][2048][64]
  unsigned short* Vt = (unsigned short*)(ws + 58720256);       // 16 MB  [bh][64][2048]
  unsigned short* Ao = xb;  // reuse (xb dead after GEMM1)

  hipLaunchKernelGGL(k_prep, dim3(8192), dim3(256), 0, stream,
                     x, xb, w_qkv, wqkvT, w_proj, wprojT);
  hipLaunchKernelGGL((k_gemm<1>), dim3(1536), dim3(256), 0, stream,
                     xb, wqkvT, b_qkv, 3072, (float*)nullptr, Qb, Kb, Vt);
  hipLaunchKernelGGL(k_attn, dim3(512), dim3(512), 0, stream, Qb, Kb, Vt, Ao);
  hipLaunchKernelGGL((k_gemm<0>), dim3(512), dim3(256), 0, stream,
                     Ao, wprojT, b_proj, 1024, out,
                     (unsigned short*)nullptr, (unsigned short*)nullptr, (unsigned short*)nullptr);
}